// Round 14
// baseline (236.814 us; speedup 1.0000x reference)
//
#include <hip/hip_runtime.h>
#include <stdint.h>

#define HW   4096
#define CIN  512

typedef __attribute__((ext_vector_type(8))) short short8;
typedef __attribute__((ext_vector_type(4))) float f32x4;
typedef __attribute__((ext_vector_type(4))) unsigned short u16x4;
typedef unsigned short u16;

#define GL16(src, ldsdst) __builtin_amdgcn_global_load_lds(                    \
    (const __attribute__((address_space(1))) void*)(src),                      \
    (__attribute__((address_space(3))) void*)(ldsdst), 16, 0, 0)

__device__ __forceinline__ u16 f2bf(float f) {
  union { float f; uint32_t u; } c; c.f = f;
  uint32_t r = (c.u + 0x7FFFu + ((c.u >> 16) & 1u)) >> 16;
  return (u16)r;
}
__device__ __forceinline__ float bf2f(u16 h) {
  union { uint32_t u; float f; } c; c.u = ((uint32_t)h) << 16;
  return c.f;
}

// ---------------------------------------------------------------------------
// x (B,C,HW) fp32  ->  xbT (B*HW, C) bf16   (64x64 tile transpose via LDS)
// ---------------------------------------------------------------------------
__global__ __launch_bounds__(256) void cast_xT(const float* __restrict__ x,
                                               u16* __restrict__ xbT) {
  __shared__ u16 t[64 * 72];
  int p0 = blockIdx.x * 64, c0 = blockIdx.y * 64, b = blockIdx.z;
  int tid = threadIdx.x, r = tid >> 2, ch = tid & 3;
  const float* xp = x + ((size_t)b * CIN + c0 + r) * HW + p0 + ch * 16;
  float4 f0 = *(const float4*)(xp + 0);
  float4 f1 = *(const float4*)(xp + 4);
  float4 f2 = *(const float4*)(xp + 8);
  float4 f3 = *(const float4*)(xp + 12);
  u16* tr = &t[r * 72 + ch * 16];
  tr[0] = f2bf(f0.x); tr[1] = f2bf(f0.y); tr[2] = f2bf(f0.z); tr[3] = f2bf(f0.w);
  tr[4] = f2bf(f1.x); tr[5] = f2bf(f1.y); tr[6] = f2bf(f1.z); tr[7] = f2bf(f1.w);
  tr[8] = f2bf(f2.x); tr[9] = f2bf(f2.y); tr[10] = f2bf(f2.z); tr[11] = f2bf(f2.w);
  tr[12] = f2bf(f3.x); tr[13] = f2bf(f3.y); tr[14] = f2bf(f3.z); tr[15] = f2bf(f3.w);
  __syncthreads();
  u16 o[16];
#pragma unroll
  for (int j = 0; j < 16; j++) o[j] = t[(ch * 16 + j) * 72 + r];
  u16* op = xbT + ((size_t)b * HW + p0 + r) * CIN + c0 + ch * 16;
  *(short8*)(op) = *(short8*)&o[0];
  *(short8*)(op + 8) = *(short8*)&o[8];
}

// ---------------------------------------------------------------------------
// weights -> bf16; wqk = [Wq*log2e; Wk] (128,512); bqk = [bq*log2e; bk]
// ---------------------------------------------------------------------------
__global__ void cast_w(const float* __restrict__ Wq, const float* __restrict__ Wk,
                       const float* __restrict__ Wv, const float* __restrict__ Wd,
                       const float* __restrict__ bq, const float* __restrict__ bk,
                       u16* __restrict__ wqk, u16* __restrict__ wv,
                       u16* __restrict__ wd, float* __restrict__ bqk) {
  const float LOG2E = 1.4426950408889634f;
  int i = blockIdx.x * 256 + threadIdx.x;
  if (i < 65536) wqk[i] = f2bf(i < 32768 ? Wq[i] * LOG2E : Wk[i - 32768]);
  if (i < 262144) { wv[i] = f2bf(Wv[i]); wd[i] = f2bf(Wd[i]); }
  if (i < 128) bqk[i] = (i < 64) ? bq[i] * LOG2E : bk[i - 64];
}

// ---------------------------------------------------------------------------
// Generic GEMM: C(M,N) = A(M,K) * BT(N,K)^T  (both bf16, K-contiguous rows)
// m97-style: 128x128 tile, BK=32, global_load_lds(16B) staging, 4 waves.
// (unchanged - proven R7..R13)
// ---------------------------------------------------------------------------
__global__ __launch_bounds__(256) void gemm_bf16(
    const u16* __restrict__ A, const u16* __restrict__ BT,
    const float* __restrict__ bias, void* __restrict__ out,
    int M, int N, int K, int mode) {
  __shared__ u16 la[128 * 32];
  __shared__ u16 lb[128 * 32];
  int tid = threadIdx.x;
  int w = tid >> 6, lane = tid & 63, m = lane & 15, g = lane >> 4;
  int wm = w >> 1, wn = w & 1;
  int m0 = blockIdx.y * 128, n0 = blockIdx.x * 128;
  int sr = lane >> 2, sc = (lane & 3) * 8;
  const u16* pa0 = A + (size_t)(m0 + w * 32 + sr) * K + sc;
  const u16* pa1 = pa0 + (size_t)16 * K;
  const u16* pb0 = BT + (size_t)(n0 + w * 32 + sr) * K + sc;
  const u16* pb1 = pb0 + (size_t)16 * K;
  u16* la0 = &la[(w * 32) * 32];
  u16* la1 = &la[(w * 32 + 16) * 32];
  u16* lb0 = &lb[(w * 32) * 32];
  u16* lb1 = &lb[(w * 32 + 16) * 32];

  f32x4 acc[4][4];
  f32x4 zero = {0.f, 0.f, 0.f, 0.f};
#pragma unroll
  for (int i = 0; i < 4; i++)
#pragma unroll
    for (int j = 0; j < 4; j++) acc[i][j] = zero;

  for (int k0 = 0; k0 < K; k0 += 32) {
    __syncthreads();
    GL16(pa0 + k0, la0);
    GL16(pa1 + k0, la1);
    GL16(pb0 + k0, lb0);
    GL16(pb1 + k0, lb1);
    __syncthreads();
    short8 af[4], bf[4];
#pragma unroll
    for (int i = 0; i < 4; i++)
      af[i] = *(const short8*)&la[(wm * 64 + i * 16 + m) * 32 + g * 8];
#pragma unroll
    for (int j = 0; j < 4; j++)
      bf[j] = *(const short8*)&lb[(wn * 64 + j * 16 + m) * 32 + g * 8];
#pragma unroll
    for (int i = 0; i < 4; i++)
#pragma unroll
      for (int j = 0; j < 4; j++)
        acc[i][j] = __builtin_amdgcn_mfma_f32_16x16x32_bf16(af[i], bf[j], acc[i][j], 0, 0, 0);
  }

#pragma unroll
  for (int i = 0; i < 4; i++) {
#pragma unroll
    for (int j = 0; j < 4; j++) {
      int row_l = m0 + wm * 64 + i * 16 + g * 4;
      int col = n0 + wn * 64 + j * 16 + m;
#pragma unroll
      for (int r = 0; r < 4; r++) {
        int row = row_l + r;
        float v = acc[i][j][r];
        if (mode == 0) {
          v += bias[col];
          ((u16*)out)[(size_t)row * N + col] = f2bf(v);
        } else {
          v += bias[row];
          size_t addr = ((size_t)(col >> 12) * M + row) * HW + (col & (HW - 1));
          if (mode == 1) ((u16*)out)[addr] = f2bf(v);
          else           ((float*)out)[addr] = v;
        }
      }
    }
  }
}

// ---------------------------------------------------------------------------
// ppass: P = exp2(Q K^T) materialized bf16 + exact row-sum reciprocals.
// R14 change (swapped-operand store): compute S^T = mfma(K_frag, Q_frag) --
// identical LDS/global loads (A and B frags share the same lane->(idx,k)
// mapping, so swapping args transposes C). Now lane holds q = qg*16+(lane&15)
// and 4 CONSECUTIVE j values (row = g*4+r) -> one packed 8B store per mfma
// (was 4 scalar 2B scatter stores), and the row-sum reduce is 1 scalar/lane
// with shfl_xor(16,32). Everything else identical to R13.
// ---------------------------------------------------------------------------
__global__ __launch_bounds__(512) void ppass(
    const u16* __restrict__ qkT, u16* __restrict__ P,
    float* __restrict__ li, int b0) {
  __shared__ u16 kl[256 * 64];
  __shared__ float red[2][64];
  int tid = threadIdx.x;
  int w = tid >> 6, lane = tid & 63, m = lane & 15, g = lane >> 4;
  int blk = blockIdx.x;
  int bb = blk >> 6, b = b0 + bb;
  int q0 = (blk & 63) << 6;
  int qg = w & 3, jh = w >> 2;
  size_t qrow = (size_t)b * HW + q0;

  short8 aq[2];
#pragma unroll
  for (int ks = 0; ks < 2; ks++)
    aq[ks] = *(const short8*)(qkT + (qrow + qg * 16 + m) * 128 + ks * 32 + g * 8);

  float lr = 0.f;
  u16* Pb = P + ((size_t)bb * HW + q0) * HW;
  const u16* kb = qkT + (size_t)b * HW * 128 + 64;
  f32x4 zero = {0.f, 0.f, 0.f, 0.f};

  for (int jp = 0; jp < 16; jp++) {
    int j0 = jp * 256;
    __syncthreads();
#pragma unroll
    for (int it = 0; it < 4; it++) {
      int c = tid + it * 512;
      int row = c >> 3, seg = c & 7;
      short8 v = *(const short8*)(kb + (size_t)(j0 + row) * 128 + seg * 8);
      *(short8*)&kl[row * 64 + ((seg ^ (row & 7)) * 8)] = v;
    }
    __syncthreads();
#pragma unroll
    for (int jt = 0; jt < 8; jt++) {
      int jr = jh * 128 + jt * 16;
      int krow = jr + m;
      f32x4 s = zero;
#pragma unroll
      for (int ks = 0; ks < 2; ks++) {
        short8 bk = *(const short8*)&kl[krow * 64 + (((ks * 4 + g) ^ (krow & 7)) * 8)];
        // swapped operands: D = K_tile^T-free transpose -> lane: q = lane&15,
        // j = jr + g*4 + r
        s = __builtin_amdgcn_mfma_f32_16x16x32_bf16(bk, aq[ks], s, 0, 0, 0);
      }
      u16x4 pk;
#pragma unroll
      for (int r = 0; r < 4; r++) {
        float p = exp2f(s[r]);
        lr += p;
        pk[r] = f2bf(p);
      }
      *(u16x4*)&Pb[(size_t)(qg * 16 + m) * HW + j0 + jr + g * 4] = pk;
    }
  }
  // per-lane lr holds sum over this wave's j for q = qg*16+m (split by g);
  // combine the 4 g-groups, then the 2 jh halves.
  lr += __shfl_xor(lr, 16);
  lr += __shfl_xor(lr, 32);
  __syncthreads();
  if (lane < 16) red[jh][qg * 16 + lane] = lr;
  __syncthreads();
  if (tid < 64) li[qrow + tid] = 1.0f / (red[0][tid] + red[1][tid]);
}

// ---------------------------------------------------------------------------
// gemm_pv: uT = gamma * (P * V^T) .* li + xbT.
// (unchanged - proven R13: 128x128 tile, K-unroll-2, chunked XCD swizzle)
// ---------------------------------------------------------------------------
__global__ __launch_bounds__(256) void gemm_pv(
    const u16* __restrict__ P, const u16* __restrict__ V,
    const float* __restrict__ li, const u16* __restrict__ xbT,
    const float* __restrict__ gamma, u16* __restrict__ uT, int b0) {
  __shared__ u16 la[2][128 * 32];
  __shared__ u16 lb[2][128 * 32];
  int tid = threadIdx.x;
  int w = tid >> 6, lane = tid & 63, m = lane & 15, g = lane >> 4;
  int wm = w >> 1, wn = w & 1;
  int total = gridDim.x * gridDim.y * gridDim.z;
  int lid = blockIdx.x + (blockIdx.y << 2) + (blockIdx.z << 7);
  int wk = (lid & 7) * (total >> 3) + (lid >> 3);
  int chan = (wk & 3) << 7;          // channel quarter: 0,128,256,384
  int q0 = ((wk >> 2) & 31) << 7;    // q-tile of 128
  int bb = wk >> 7, b = b0 + bb;
  int sr = lane >> 2, sc = (lane & 3) * 8;

  const u16* pa0 = P + ((size_t)bb * HW + q0 + w * 32 + sr) * HW + sc;
  const u16* pa1 = pa0 + (size_t)16 * HW;
  const u16* pb0 = V + ((size_t)b * CIN + chan + w * 32 + sr) * HW + sc;
  const u16* pb1 = pb0 + (size_t)16 * HW;

  f32x4 acc[4][4];
  f32x4 zero = {0.f, 0.f, 0.f, 0.f};
#pragma unroll
  for (int i = 0; i < 4; i++)
#pragma unroll
    for (int j = 0; j < 4; j++) acc[i][j] = zero;

  for (int k0 = 0; k0 < HW; k0 += 64) {
    __syncthreads();
#pragma unroll
    for (int c = 0; c < 2; c++) {
      int kk = k0 + c * 32;
      GL16(pa0 + kk, &la[c][(w * 32) * 32]);
      GL16(pa1 + kk, &la[c][(w * 32 + 16) * 32]);
      GL16(pb0 + kk, &lb[c][(w * 32) * 32]);
      GL16(pb1 + kk, &lb[c][(w * 32 + 16) * 32]);
    }
    __syncthreads();
#pragma unroll
    for (int c = 0; c < 2; c++) {
      short8 af[4], bf[4];
#pragma unroll
      for (int i = 0; i < 4; i++)
        af[i] = *(const short8*)&la[c][(wm * 64 + i * 16 + m) * 32 + g * 8];
#pragma unroll
      for (int j = 0; j < 4; j++)
        bf[j] = *(const short8*)&lb[c][(wn * 64 + j * 16 + m) * 32 + g * 8];
#pragma unroll
      for (int i = 0; i < 4; i++)
#pragma unroll
        for (int j = 0; j < 4; j++)
          acc[i][j] = __builtin_amdgcn_mfma_f32_16x16x32_bf16(af[i], bf[j], acc[i][j], 0, 0, 0);
    }
  }

  float gm = gamma[0];
#pragma unroll
  for (int i = 0; i < 4; i++) {
#pragma unroll
    for (int j = 0; j < 4; j++) {
#pragma unroll
      for (int r = 0; r < 4; r++) {
        int q = q0 + wm * 64 + i * 16 + g * 4 + r;
        int c = chan + wn * 64 + j * 16 + m;
        size_t row = (size_t)b * HW + q;
        float o = acc[i][j][r] * li[row];
        float xv = bf2f(xbT[row * CIN + c]);
        uT[row * CIN + c] = f2bf(gm * o + xv);
      }
    }
  }
}

// ---------------------------------------------------------------------------
extern "C" void kernel_launch(void* const* d_in, const int* in_sizes, int n_in,
                              void* d_out, int out_size, void* d_ws, size_t ws_size,
                              hipStream_t stream) {
  const float* x     = (const float*)d_in[0];
  const float* Wq    = (const float*)d_in[1];
  const float* bq    = (const float*)d_in[2];
  const float* Wk    = (const float*)d_in[3];
  const float* bk    = (const float*)d_in[4];
  const float* Wv    = (const float*)d_in[5];
  const float* bv    = (const float*)d_in[6];
  const float* gamma = (const float*)d_in[7];
  const float* Wd    = (const float*)d_in[8];
  const float* bd    = (const float*)d_in[9];

  char* ws = (char*)d_ws;
  size_t off = 0;
  auto alloc = [&](size_t bytes) {
    void* p = ws + off;
    off += (bytes + 255) & ~(size_t)255;
    return p;
  };
  u16*   xbT = (u16*)alloc((size_t)16384 * 512 * 2);
  u16*   qkT = (u16*)alloc((size_t)16384 * 128 * 2);
  u16*   vb  = (u16*)alloc((size_t)16384 * 512 * 2);
  u16*   uT  = (u16*)alloc((size_t)16384 * 512 * 2);
  u16*   wqk = (u16*)alloc((size_t)65536 * 2);
  u16*   wvb = (u16*)alloc((size_t)262144 * 2);
  u16*   wdb = (u16*)alloc((size_t)262144 * 2);
  float* bqk = (float*)alloc(128 * 4);
  float* li  = (float*)alloc((size_t)16384 * 4);
  size_t PB = (size_t)HW * HW * 2;
  int nb = 0;
  if      (off + 4 * PB <= ws_size) nb = 4;
  else if (off + 2 * PB <= ws_size) nb = 2;
  else if (off + 1 * PB <= ws_size) nb = 1;
  if (nb == 0) return;  // workspace too small -> poison stays -> loud failure
  u16* Pbuf = (u16*)alloc(nb * PB);

  cast_xT<<<dim3(64, 8, 4), 256, 0, stream>>>(x, xbT);
  cast_w<<<1024, 256, 0, stream>>>(Wq, Wk, Wv, Wd, bq, bk, wqk, wvb, wdb, bqk);
  // qkT (16384,128) = xbT * wqk^T
  gemm_bf16<<<dim3(1, 128), 256, 0, stream>>>(xbT, wqk, bqk, qkT, 16384, 128, 512, 0);
  // v (B,512,HW) = Wv * x
  gemm_bf16<<<dim3(128, 4), 256, 0, stream>>>(wvb, xbT, bv, vb, 512, 16384, 512, 1);
  // attention: P materialize + PV GEMM (staged by batch groups of nb)
  for (int b0 = 0; b0 < 4; b0 += nb) {
    ppass<<<dim3(nb * 64), 512, 0, stream>>>(qkT, Pbuf, li, b0);
    gemm_pv<<<dim3(4, 32, nb), 256, 0, stream>>>(Pbuf, vb, li, xbT, gamma, uT, b0);
  }
  // pam_out (B,512,HW) fp32 = Wd * u
  gemm_bf16<<<dim3(128, 4), 256, 0, stream>>>(wdb, uT, bd, d_out, 512, 16384, 512, 2);
}

// Round 15
// 203.883 us; speedup vs baseline: 1.1615x; 1.1615x over previous
//
#include <hip/hip_runtime.h>
#include <stdint.h>

#define HW   4096
#define CIN  512

typedef __attribute__((ext_vector_type(8))) short short8;
typedef __attribute__((ext_vector_type(4))) float f32x4;
typedef unsigned short u16;

#define GL16(src, ldsdst) __builtin_amdgcn_global_load_lds(                    \
    (const __attribute__((address_space(1))) void*)(src),                      \
    (__attribute__((address_space(3))) void*)(ldsdst), 16, 0, 0)

__device__ __forceinline__ u16 f2bf(float f) {
  union { float f; uint32_t u; } c; c.f = f;
  uint32_t r = (c.u + 0x7FFFu + ((c.u >> 16) & 1u)) >> 16;
  return (u16)r;
}
__device__ __forceinline__ float bf2f(u16 h) {
  union { uint32_t u; float f; } c; c.u = ((uint32_t)h) << 16;
  return c.f;
}

// ---------------------------------------------------------------------------
// x (B,C,HW) fp32  ->  xbT (B*HW, C) bf16   (64x64 tile transpose via LDS)
// ---------------------------------------------------------------------------
__global__ __launch_bounds__(256) void cast_xT(const float* __restrict__ x,
                                               u16* __restrict__ xbT) {
  __shared__ u16 t[64 * 72];
  int p0 = blockIdx.x * 64, c0 = blockIdx.y * 64, b = blockIdx.z;
  int tid = threadIdx.x, r = tid >> 2, ch = tid & 3;
  const float* xp = x + ((size_t)b * CIN + c0 + r) * HW + p0 + ch * 16;
  float4 f0 = *(const float4*)(xp + 0);
  float4 f1 = *(const float4*)(xp + 4);
  float4 f2 = *(const float4*)(xp + 8);
  float4 f3 = *(const float4*)(xp + 12);
  u16* tr = &t[r * 72 + ch * 16];
  tr[0] = f2bf(f0.x); tr[1] = f2bf(f0.y); tr[2] = f2bf(f0.z); tr[3] = f2bf(f0.w);
  tr[4] = f2bf(f1.x); tr[5] = f2bf(f1.y); tr[6] = f2bf(f1.z); tr[7] = f2bf(f1.w);
  tr[8] = f2bf(f2.x); tr[9] = f2bf(f2.y); tr[10] = f2bf(f2.z); tr[11] = f2bf(f2.w);
  tr[12] = f2bf(f3.x); tr[13] = f2bf(f3.y); tr[14] = f2bf(f3.z); tr[15] = f2bf(f3.w);
  __syncthreads();
  u16 o[16];
#pragma unroll
  for (int j = 0; j < 16; j++) o[j] = t[(ch * 16 + j) * 72 + r];
  u16* op = xbT + ((size_t)b * HW + p0 + r) * CIN + c0 + ch * 16;
  *(short8*)(op) = *(short8*)&o[0];
  *(short8*)(op + 8) = *(short8*)&o[8];
}

// ---------------------------------------------------------------------------
// weights -> bf16; wqk = [Wq*log2e; Wk] (128,512); bqk = [bq*log2e; bk]
// ---------------------------------------------------------------------------
__global__ void cast_w(const float* __restrict__ Wq, const float* __restrict__ Wk,
                       const float* __restrict__ Wv, const float* __restrict__ Wd,
                       const float* __restrict__ bq, const float* __restrict__ bk,
                       u16* __restrict__ wqk, u16* __restrict__ wv,
                       u16* __restrict__ wd, float* __restrict__ bqk) {
  const float LOG2E = 1.4426950408889634f;
  int i = blockIdx.x * 256 + threadIdx.x;
  if (i < 65536) wqk[i] = f2bf(i < 32768 ? Wq[i] * LOG2E : Wk[i - 32768]);
  if (i < 262144) { wv[i] = f2bf(Wv[i]); wd[i] = f2bf(Wd[i]); }
  if (i < 128) bqk[i] = (i < 64) ? bq[i] * LOG2E : bk[i - 64];
}

// ---------------------------------------------------------------------------
// Generic GEMM: C(M,N) = A(M,K) * BT(N,K)^T  (both bf16, K-contiguous rows)
// m97-style: 128x128 tile, BK=32, global_load_lds(16B) staging, 4 waves.
// (unchanged - proven R7..R13)
// ---------------------------------------------------------------------------
__global__ __launch_bounds__(256) void gemm_bf16(
    const u16* __restrict__ A, const u16* __restrict__ BT,
    const float* __restrict__ bias, void* __restrict__ out,
    int M, int N, int K, int mode) {
  __shared__ u16 la[128 * 32];
  __shared__ u16 lb[128 * 32];
  int tid = threadIdx.x;
  int w = tid >> 6, lane = tid & 63, m = lane & 15, g = lane >> 4;
  int wm = w >> 1, wn = w & 1;
  int m0 = blockIdx.y * 128, n0 = blockIdx.x * 128;
  int sr = lane >> 2, sc = (lane & 3) * 8;
  const u16* pa0 = A + (size_t)(m0 + w * 32 + sr) * K + sc;
  const u16* pa1 = pa0 + (size_t)16 * K;
  const u16* pb0 = BT + (size_t)(n0 + w * 32 + sr) * K + sc;
  const u16* pb1 = pb0 + (size_t)16 * K;
  u16* la0 = &la[(w * 32) * 32];
  u16* la1 = &la[(w * 32 + 16) * 32];
  u16* lb0 = &lb[(w * 32) * 32];
  u16* lb1 = &lb[(w * 32 + 16) * 32];

  f32x4 acc[4][4];
  f32x4 zero = {0.f, 0.f, 0.f, 0.f};
#pragma unroll
  for (int i = 0; i < 4; i++)
#pragma unroll
    for (int j = 0; j < 4; j++) acc[i][j] = zero;

  for (int k0 = 0; k0 < K; k0 += 32) {
    __syncthreads();
    GL16(pa0 + k0, la0);
    GL16(pa1 + k0, la1);
    GL16(pb0 + k0, lb0);
    GL16(pb1 + k0, lb1);
    __syncthreads();
    short8 af[4], bf[4];
#pragma unroll
    for (int i = 0; i < 4; i++)
      af[i] = *(const short8*)&la[(wm * 64 + i * 16 + m) * 32 + g * 8];
#pragma unroll
    for (int j = 0; j < 4; j++)
      bf[j] = *(const short8*)&lb[(wn * 64 + j * 16 + m) * 32 + g * 8];
#pragma unroll
    for (int i = 0; i < 4; i++)
#pragma unroll
      for (int j = 0; j < 4; j++)
        acc[i][j] = __builtin_amdgcn_mfma_f32_16x16x32_bf16(af[i], bf[j], acc[i][j], 0, 0, 0);
  }

#pragma unroll
  for (int i = 0; i < 4; i++) {
#pragma unroll
    for (int j = 0; j < 4; j++) {
      int row_l = m0 + wm * 64 + i * 16 + g * 4;
      int col = n0 + wn * 64 + j * 16 + m;
#pragma unroll
      for (int r = 0; r < 4; r++) {
        int row = row_l + r;
        float v = acc[i][j][r];
        if (mode == 0) {
          v += bias[col];
          ((u16*)out)[(size_t)row * N + col] = f2bf(v);
        } else {
          v += bias[row];
          size_t addr = ((size_t)(col >> 12) * M + row) * HW + (col & (HW - 1));
          if (mode == 1) ((u16*)out)[addr] = f2bf(v);
          else           ((float*)out)[addr] = v;
        }
      }
    }
  }
}

// ---------------------------------------------------------------------------
// ppass: P = exp2(Q K^T) materialized bf16 + exact row-sum reciprocals.
// (REVERTED to R13-exact - R14's packed-store variant regressed ~21 us)
// ---------------------------------------------------------------------------
__global__ __launch_bounds__(512) void ppass(
    const u16* __restrict__ qkT, u16* __restrict__ P,
    float* __restrict__ li, int b0) {
  __shared__ u16 kl[256 * 64];
  __shared__ float red[2][64];
  int tid = threadIdx.x;
  int w = tid >> 6, lane = tid & 63, m = lane & 15, g = lane >> 4;
  int blk = blockIdx.x;
  int bb = blk >> 6, b = b0 + bb;
  int q0 = (blk & 63) << 6;
  int qg = w & 3, jh = w >> 2;
  size_t qrow = (size_t)b * HW + q0;

  short8 aq[2];
#pragma unroll
  for (int ks = 0; ks < 2; ks++)
    aq[ks] = *(const short8*)(qkT + (qrow + qg * 16 + m) * 128 + ks * 32 + g * 8);

  float lr[4] = {0.f, 0.f, 0.f, 0.f};
  u16* Pb = P + ((size_t)bb * HW + q0) * HW;
  const u16* kb = qkT + (size_t)b * HW * 128 + 64;
  f32x4 zero = {0.f, 0.f, 0.f, 0.f};

  for (int jp = 0; jp < 16; jp++) {
    int j0 = jp * 256;
    __syncthreads();
#pragma unroll
    for (int it = 0; it < 4; it++) {
      int c = tid + it * 512;
      int row = c >> 3, seg = c & 7;
      short8 v = *(const short8*)(kb + (size_t)(j0 + row) * 128 + seg * 8);
      *(short8*)&kl[row * 64 + ((seg ^ (row & 7)) * 8)] = v;
    }
    __syncthreads();
#pragma unroll
    for (int jt = 0; jt < 8; jt++) {
      int jr = jh * 128 + jt * 16;
      int krow = jr + m;
      f32x4 s = zero;
#pragma unroll
      for (int ks = 0; ks < 2; ks++) {
        short8 bk = *(const short8*)&kl[krow * 64 + (((ks * 4 + g) ^ (krow & 7)) * 8)];
        s = __builtin_amdgcn_mfma_f32_16x16x32_bf16(aq[ks], bk, s, 0, 0, 0);
      }
      int j = j0 + jr + m;
#pragma unroll
      for (int r = 0; r < 4; r++) {
        float p = exp2f(s[r]);
        lr[r] += p;
        Pb[(size_t)(qg * 16 + g * 4 + r) * HW + j] = f2bf(p);
      }
    }
  }
#pragma unroll
  for (int r = 0; r < 4; r++) {
#pragma unroll
    for (int off = 1; off < 16; off <<= 1)
      lr[r] += __shfl_xor(lr[r], off);
  }
  __syncthreads();
  if (m == 0) {
#pragma unroll
    for (int r = 0; r < 4; r++) red[jh][qg * 16 + g * 4 + r] = lr[r];
  }
  __syncthreads();
  if (tid < 64) li[qrow + tid] = 1.0f / (red[0][tid] + red[1][tid]);
}

// ---------------------------------------------------------------------------
// gemm_pv: uT = gamma * (P * V^T) .* li + xbT.
// R13 structure, ONLY change: K-unroll 2 -> 4 chunks per barrier pair.
//   stage(k..k+127) -> barrier -> compute all 4 chunks -> barrier.
// All chunks staged AND consumed inside one barrier pair (race-free).
// Barrier events halve again (64 -> 32); 64 MFMAs/wave per pair.
// LDS 64 KB (2 blocks/CU preserved - grid is the binding limit).
//   tile 128q x 128c, 4 waves 2x2, wave 64x64 = 4x4 frags.
//   grid (4 chan, 32 qtiles, nb) = 512 blocks.
// Chunked bijective XCD swizzle (proven R10..R13).
// ---------------------------------------------------------------------------
__global__ __launch_bounds__(256) void gemm_pv(
    const u16* __restrict__ P, const u16* __restrict__ V,
    const float* __restrict__ li, const u16* __restrict__ xbT,
    const float* __restrict__ gamma, u16* __restrict__ uT, int b0) {
  __shared__ u16 la[4][128 * 32];
  __shared__ u16 lb[4][128 * 32];
  int tid = threadIdx.x;
  int w = tid >> 6, lane = tid & 63, m = lane & 15, g = lane >> 4;
  int wm = w >> 1, wn = w & 1;
  int total = gridDim.x * gridDim.y * gridDim.z;
  int lid = blockIdx.x + (blockIdx.y << 2) + (blockIdx.z << 7);
  int wk = (lid & 7) * (total >> 3) + (lid >> 3);
  int chan = (wk & 3) << 7;          // channel quarter: 0,128,256,384
  int q0 = ((wk >> 2) & 31) << 7;    // q-tile of 128
  int bb = wk >> 7, b = b0 + bb;
  int sr = lane >> 2, sc = (lane & 3) * 8;

  const u16* pa0 = P + ((size_t)bb * HW + q0 + w * 32 + sr) * HW + sc;
  const u16* pa1 = pa0 + (size_t)16 * HW;
  const u16* pb0 = V + ((size_t)b * CIN + chan + w * 32 + sr) * HW + sc;
  const u16* pb1 = pb0 + (size_t)16 * HW;

  f32x4 acc[4][4];
  f32x4 zero = {0.f, 0.f, 0.f, 0.f};
#pragma unroll
  for (int i = 0; i < 4; i++)
#pragma unroll
    for (int j = 0; j < 4; j++) acc[i][j] = zero;

  for (int k0 = 0; k0 < HW; k0 += 128) {
    __syncthreads();
#pragma unroll
    for (int c = 0; c < 4; c++) {
      int kk = k0 + c * 32;
      GL16(pa0 + kk, &la[c][(w * 32) * 32]);
      GL16(pa1 + kk, &la[c][(w * 32 + 16) * 32]);
      GL16(pb0 + kk, &lb[c][(w * 32) * 32]);
      GL16(pb1 + kk, &lb[c][(w * 32 + 16) * 32]);
    }
    __syncthreads();
#pragma unroll
    for (int c = 0; c < 4; c++) {
      short8 af[4], bf[4];
#pragma unroll
      for (int i = 0; i < 4; i++)
        af[i] = *(const short8*)&la[c][(wm * 64 + i * 16 + m) * 32 + g * 8];
#pragma unroll
      for (int j = 0; j < 4; j++)
        bf[j] = *(const short8*)&lb[c][(wn * 64 + j * 16 + m) * 32 + g * 8];
#pragma unroll
      for (int i = 0; i < 4; i++)
#pragma unroll
        for (int j = 0; j < 4; j++)
          acc[i][j] = __builtin_amdgcn_mfma_f32_16x16x32_bf16(af[i], bf[j], acc[i][j], 0, 0, 0);
    }
  }

  float gm = gamma[0];
#pragma unroll
  for (int i = 0; i < 4; i++) {
#pragma unroll
    for (int j = 0; j < 4; j++) {
#pragma unroll
      for (int r = 0; r < 4; r++) {
        int q = q0 + wm * 64 + i * 16 + g * 4 + r;
        int c = chan + wn * 64 + j * 16 + m;
        size_t row = (size_t)b * HW + q;
        float o = acc[i][j][r] * li[row];
        float xv = bf2f(xbT[row * CIN + c]);
        uT[row * CIN + c] = f2bf(gm * o + xv);
      }
    }
  }
}

// ---------------------------------------------------------------------------
extern "C" void kernel_launch(void* const* d_in, const int* in_sizes, int n_in,
                              void* d_out, int out_size, void* d_ws, size_t ws_size,
                              hipStream_t stream) {
  const float* x     = (const float*)d_in[0];
  const float* Wq    = (const float*)d_in[1];
  const float* bq    = (const float*)d_in[2];
  const float* Wk    = (const float*)d_in[3];
  const float* bk    = (const float*)d_in[4];
  const float* Wv    = (const float*)d_in[5];
  const float* bv    = (const float*)d_in[6];
  const float* gamma = (const float*)d_in[7];
  const float* Wd    = (const float*)d_in[8];
  const float* bd    = (const float*)d_in[9];

  char* ws = (char*)d_ws;
  size_t off = 0;
  auto alloc = [&](size_t bytes) {
    void* p = ws + off;
    off += (bytes + 255) & ~(size_t)255;
    return p;
  };
  u16*   xbT = (u16*)alloc((size_t)16384 * 512 * 2);
  u16*   qkT = (u16*)alloc((size_t)16384 * 128 * 2);
  u16*   vb  = (u16*)alloc((size_t)16384 * 512 * 2);
  u16*   uT  = (u16*)alloc((size_t)16384 * 512 * 2);
  u16*   wqk = (u16*)alloc((size_t)65536 * 2);
  u16*   wvb = (u16*)alloc((size_t)262144 * 2);
  u16*   wdb = (u16*)alloc((size_t)262144 * 2);
  float* bqk = (float*)alloc(128 * 4);
  float* li  = (float*)alloc((size_t)16384 * 4);
  size_t PB = (size_t)HW * HW * 2;
  int nb = 0;
  if      (off + 4 * PB <= ws_size) nb = 4;
  else if (off + 2 * PB <= ws_size) nb = 2;
  else if (off + 1 * PB <= ws_size) nb = 1;
  if (nb == 0) return;  // workspace too small -> poison stays -> loud failure
  u16* Pbuf = (u16*)alloc(nb * PB);

  cast_xT<<<dim3(64, 8, 4), 256, 0, stream>>>(x, xbT);
  cast_w<<<1024, 256, 0, stream>>>(Wq, Wk, Wv, Wd, bq, bk, wqk, wvb, wdb, bqk);
  // qkT (16384,128) = xbT * wqk^T
  gemm_bf16<<<dim3(1, 128), 256, 0, stream>>>(xbT, wqk, bqk, qkT, 16384, 128, 512, 0);
  // v (B,512,HW) = Wv * x
  gemm_bf16<<<dim3(128, 4), 256, 0, stream>>>(wvb, xbT, bv, vb, 512, 16384, 512, 1);
  // attention: P materialize + PV GEMM (staged by batch groups of nb)
  for (int b0 = 0; b0 < 4; b0 += nb) {
    ppass<<<dim3(nb * 64), 512, 0, stream>>>(qkT, Pbuf, li, b0);
    gemm_pv<<<dim3(4, 32, nb), 256, 0, stream>>>(Pbuf, vb, li, xbT, gamma, uT, b0);
  }
  // pam_out (B,512,HW) fp32 = Wd * u
  gemm_bf16<<<dim3(128, 4), 256, 0, stream>>>(wdb, uT, bd, d_out, 512, 16384, 512, 2);
}

// Round 16
// 193.551 us; speedup vs baseline: 1.2235x; 1.0534x over previous
//
#include <hip/hip_runtime.h>
#include <stdint.h>

#define HW   4096
#define CIN  512

typedef __attribute__((ext_vector_type(8))) short short8;
typedef __attribute__((ext_vector_type(4))) float f32x4;
typedef unsigned short u16;

#define GL16(src, ldsdst) __builtin_amdgcn_global_load_lds(                    \
    (const __attribute__((address_space(1))) void*)(src),                      \
    (__attribute__((address_space(3))) void*)(ldsdst), 16, 0, 0)

__device__ __forceinline__ u16 f2bf(float f) {
  union { float f; uint32_t u; } c; c.f = f;
  uint32_t r = (c.u + 0x7FFFu + ((c.u >> 16) & 1u)) >> 16;
  return (u16)r;
}
__device__ __forceinline__ float bf2f(u16 h) {
  union { uint32_t u; float f; } c; c.u = ((uint32_t)h) << 16;
  return c.f;
}

// ---------------------------------------------------------------------------
// x (B,C,HW) fp32  ->  xbT (B*HW, C) bf16   (64x64 tile transpose via LDS)
// ---------------------------------------------------------------------------
__global__ __launch_bounds__(256) void cast_xT(const float* __restrict__ x,
                                               u16* __restrict__ xbT) {
  __shared__ u16 t[64 * 72];
  int p0 = blockIdx.x * 64, c0 = blockIdx.y * 64, b = blockIdx.z;
  int tid = threadIdx.x, r = tid >> 2, ch = tid & 3;
  const float* xp = x + ((size_t)b * CIN + c0 + r) * HW + p0 + ch * 16;
  float4 f0 = *(const float4*)(xp + 0);
  float4 f1 = *(const float4*)(xp + 4);
  float4 f2 = *(const float4*)(xp + 8);
  float4 f3 = *(const float4*)(xp + 12);
  u16* tr = &t[r * 72 + ch * 16];
  tr[0] = f2bf(f0.x); tr[1] = f2bf(f0.y); tr[2] = f2bf(f0.z); tr[3] = f2bf(f0.w);
  tr[4] = f2bf(f1.x); tr[5] = f2bf(f1.y); tr[6] = f2bf(f1.z); tr[7] = f2bf(f1.w);
  tr[8] = f2bf(f2.x); tr[9] = f2bf(f2.y); tr[10] = f2bf(f2.z); tr[11] = f2bf(f2.w);
  tr[12] = f2bf(f3.x); tr[13] = f2bf(f3.y); tr[14] = f2bf(f3.z); tr[15] = f2bf(f3.w);
  __syncthreads();
  u16 o[16];
#pragma unroll
  for (int j = 0; j < 16; j++) o[j] = t[(ch * 16 + j) * 72 + r];
  u16* op = xbT + ((size_t)b * HW + p0 + r) * CIN + c0 + ch * 16;
  *(short8*)(op) = *(short8*)&o[0];
  *(short8*)(op + 8) = *(short8*)&o[8];
}

// ---------------------------------------------------------------------------
// weights -> bf16; wqk = [Wq*log2e; Wk] (128,512); bqk = [bq*log2e; bk]
// ---------------------------------------------------------------------------
__global__ void cast_w(const float* __restrict__ Wq, const float* __restrict__ Wk,
                       const float* __restrict__ Wv, const float* __restrict__ Wd,
                       const float* __restrict__ bq, const float* __restrict__ bk,
                       u16* __restrict__ wqk, u16* __restrict__ wv,
                       u16* __restrict__ wd, float* __restrict__ bqk) {
  const float LOG2E = 1.4426950408889634f;
  int i = blockIdx.x * 256 + threadIdx.x;
  if (i < 65536) wqk[i] = f2bf(i < 32768 ? Wq[i] * LOG2E : Wk[i - 32768]);
  if (i < 262144) { wv[i] = f2bf(Wv[i]); wd[i] = f2bf(Wd[i]); }
  if (i < 128) bqk[i] = (i < 64) ? bq[i] * LOG2E : bk[i - 64];
}

// ---------------------------------------------------------------------------
// Generic GEMM: C(M,N) = A(M,K) * BT(N,K)^T  (both bf16, K-contiguous rows)
// R16: R15's thrice-proven K-unroll-4 applied (stage 4 chunks -> barrier ->
// compute 4 -> barrier). LDS 64 KB (grid 512 = 2 blocks/CU anyway).
// K=512 -> 4 barrier pairs (was 16). Staging/compute per-chunk identical.
// ---------------------------------------------------------------------------
__global__ __launch_bounds__(256) void gemm_bf16(
    const u16* __restrict__ A, const u16* __restrict__ BT,
    const float* __restrict__ bias, void* __restrict__ out,
    int M, int N, int K, int mode) {
  __shared__ u16 la[4][128 * 32];
  __shared__ u16 lb[4][128 * 32];
  int tid = threadIdx.x;
  int w = tid >> 6, lane = tid & 63, m = lane & 15, g = lane >> 4;
  int wm = w >> 1, wn = w & 1;
  int m0 = blockIdx.y * 128, n0 = blockIdx.x * 128;
  int sr = lane >> 2, sc = (lane & 3) * 8;
  const u16* pa0 = A + (size_t)(m0 + w * 32 + sr) * K + sc;
  const u16* pa1 = pa0 + (size_t)16 * K;
  const u16* pb0 = BT + (size_t)(n0 + w * 32 + sr) * K + sc;
  const u16* pb1 = pb0 + (size_t)16 * K;

  f32x4 acc[4][4];
  f32x4 zero = {0.f, 0.f, 0.f, 0.f};
#pragma unroll
  for (int i = 0; i < 4; i++)
#pragma unroll
    for (int j = 0; j < 4; j++) acc[i][j] = zero;

  for (int k0 = 0; k0 < K; k0 += 128) {
    __syncthreads();
#pragma unroll
    for (int c = 0; c < 4; c++) {
      int kk = k0 + c * 32;
      GL16(pa0 + kk, &la[c][(w * 32) * 32]);
      GL16(pa1 + kk, &la[c][(w * 32 + 16) * 32]);
      GL16(pb0 + kk, &lb[c][(w * 32) * 32]);
      GL16(pb1 + kk, &lb[c][(w * 32 + 16) * 32]);
    }
    __syncthreads();
#pragma unroll
    for (int c = 0; c < 4; c++) {
      short8 af[4], bf[4];
#pragma unroll
      for (int i = 0; i < 4; i++)
        af[i] = *(const short8*)&la[c][(wm * 64 + i * 16 + m) * 32 + g * 8];
#pragma unroll
      for (int j = 0; j < 4; j++)
        bf[j] = *(const short8*)&lb[c][(wn * 64 + j * 16 + m) * 32 + g * 8];
#pragma unroll
      for (int i = 0; i < 4; i++)
#pragma unroll
        for (int j = 0; j < 4; j++)
          acc[i][j] = __builtin_amdgcn_mfma_f32_16x16x32_bf16(af[i], bf[j], acc[i][j], 0, 0, 0);
    }
  }

#pragma unroll
  for (int i = 0; i < 4; i++) {
#pragma unroll
    for (int j = 0; j < 4; j++) {
      int row_l = m0 + wm * 64 + i * 16 + g * 4;
      int col = n0 + wn * 64 + j * 16 + m;
#pragma unroll
      for (int r = 0; r < 4; r++) {
        int row = row_l + r;
        float v = acc[i][j][r];
        if (mode == 0) {
          v += bias[col];
          ((u16*)out)[(size_t)row * N + col] = f2bf(v);
        } else {
          v += bias[row];
          size_t addr = ((size_t)(col >> 12) * M + row) * HW + (col & (HW - 1));
          if (mode == 1) ((u16*)out)[addr] = f2bf(v);
          else           ((float*)out)[addr] = v;
        }
      }
    }
  }
}

// ---------------------------------------------------------------------------
// ppass: P = exp2(Q K^T) materialized bf16 + exact row-sum reciprocals.
// R16 change: q-split 64 -> 32 rows/block => 512 blocks = 2 blocks/CU
// (was 1) so co-resident blocks hide each other's barrier drains.
// Waves: qg = w&1 (2 x 16 q-rows), jh = w>>1 (4 j-quarters of each
// 256-row K panel). Same total work; full row sums stay in-block.
// K-panel staging identical to R13 (proven).
// ---------------------------------------------------------------------------
__global__ __launch_bounds__(512) void ppass(
    const u16* __restrict__ qkT, u16* __restrict__ P,
    float* __restrict__ li, int b0) {
  __shared__ u16 kl[256 * 64];
  __shared__ float red[4][32];
  int tid = threadIdx.x;
  int w = tid >> 6, lane = tid & 63, m = lane & 15, g = lane >> 4;
  int blk = blockIdx.x;
  int bb = blk >> 7, b = b0 + bb;
  int q0 = (blk & 127) << 5;
  int qg = w & 1, jh = w >> 1;
  size_t qrow = (size_t)b * HW + q0;

  short8 aq[2];
#pragma unroll
  for (int ks = 0; ks < 2; ks++)
    aq[ks] = *(const short8*)(qkT + (qrow + qg * 16 + m) * 128 + ks * 32 + g * 8);

  float lr[4] = {0.f, 0.f, 0.f, 0.f};
  u16* Pb = P + ((size_t)bb * HW + q0) * HW;
  const u16* kb = qkT + (size_t)b * HW * 128 + 64;
  f32x4 zero = {0.f, 0.f, 0.f, 0.f};

  for (int jp = 0; jp < 16; jp++) {
    int j0 = jp * 256;
    __syncthreads();
#pragma unroll
    for (int it = 0; it < 4; it++) {
      int c = tid + it * 512;
      int row = c >> 3, seg = c & 7;
      short8 v = *(const short8*)(kb + (size_t)(j0 + row) * 128 + seg * 8);
      *(short8*)&kl[row * 64 + ((seg ^ (row & 7)) * 8)] = v;
    }
    __syncthreads();
#pragma unroll
    for (int jt = 0; jt < 4; jt++) {
      int jr = jh * 64 + jt * 16;
      int krow = jr + m;
      f32x4 s = zero;
#pragma unroll
      for (int ks = 0; ks < 2; ks++) {
        short8 bk = *(const short8*)&kl[krow * 64 + (((ks * 4 + g) ^ (krow & 7)) * 8)];
        s = __builtin_amdgcn_mfma_f32_16x16x32_bf16(aq[ks], bk, s, 0, 0, 0);
      }
      int j = j0 + jr + m;
#pragma unroll
      for (int r = 0; r < 4; r++) {
        float p = exp2f(s[r]);
        lr[r] += p;
        Pb[(size_t)(qg * 16 + g * 4 + r) * HW + j] = f2bf(p);
      }
    }
  }
#pragma unroll
  for (int r = 0; r < 4; r++) {
#pragma unroll
    for (int off = 1; off < 16; off <<= 1)
      lr[r] += __shfl_xor(lr[r], off);
  }
  __syncthreads();
  if (m == 0) {
#pragma unroll
    for (int r = 0; r < 4; r++) red[jh][qg * 16 + g * 4 + r] = lr[r];
  }
  __syncthreads();
  if (tid < 32)
    li[qrow + tid] = 1.0f / (red[0][tid] + red[1][tid] + red[2][tid] + red[3][tid]);
}

// ---------------------------------------------------------------------------
// gemm_pv: uT = gamma * (P * V^T) .* li + xbT.
// (unchanged - proven R15: 128x128 tile, K-unroll-4, chunked XCD swizzle)
// ---------------------------------------------------------------------------
__global__ __launch_bounds__(256) void gemm_pv(
    const u16* __restrict__ P, const u16* __restrict__ V,
    const float* __restrict__ li, const u16* __restrict__ xbT,
    const float* __restrict__ gamma, u16* __restrict__ uT, int b0) {
  __shared__ u16 la[4][128 * 32];
  __shared__ u16 lb[4][128 * 32];
  int tid = threadIdx.x;
  int w = tid >> 6, lane = tid & 63, m = lane & 15, g = lane >> 4;
  int wm = w >> 1, wn = w & 1;
  int total = gridDim.x * gridDim.y * gridDim.z;
  int lid = blockIdx.x + (blockIdx.y << 2) + (blockIdx.z << 7);
  int wk = (lid & 7) * (total >> 3) + (lid >> 3);
  int chan = (wk & 3) << 7;          // channel quarter: 0,128,256,384
  int q0 = ((wk >> 2) & 31) << 7;    // q-tile of 128
  int bb = wk >> 7, b = b0 + bb;
  int sr = lane >> 2, sc = (lane & 3) * 8;

  const u16* pa0 = P + ((size_t)bb * HW + q0 + w * 32 + sr) * HW + sc;
  const u16* pa1 = pa0 + (size_t)16 * HW;
  const u16* pb0 = V + ((size_t)b * CIN + chan + w * 32 + sr) * HW + sc;
  const u16* pb1 = pb0 + (size_t)16 * HW;

  f32x4 acc[4][4];
  f32x4 zero = {0.f, 0.f, 0.f, 0.f};
#pragma unroll
  for (int i = 0; i < 4; i++)
#pragma unroll
    for (int j = 0; j < 4; j++) acc[i][j] = zero;

  for (int k0 = 0; k0 < HW; k0 += 128) {
    __syncthreads();
#pragma unroll
    for (int c = 0; c < 4; c++) {
      int kk = k0 + c * 32;
      GL16(pa0 + kk, &la[c][(w * 32) * 32]);
      GL16(pa1 + kk, &la[c][(w * 32 + 16) * 32]);
      GL16(pb0 + kk, &lb[c][(w * 32) * 32]);
      GL16(pb1 + kk, &lb[c][(w * 32 + 16) * 32]);
    }
    __syncthreads();
#pragma unroll
    for (int c = 0; c < 4; c++) {
      short8 af[4], bf[4];
#pragma unroll
      for (int i = 0; i < 4; i++)
        af[i] = *(const short8*)&la[c][(wm * 64 + i * 16 + m) * 32 + g * 8];
#pragma unroll
      for (int j = 0; j < 4; j++)
        bf[j] = *(const short8*)&lb[c][(wn * 64 + j * 16 + m) * 32 + g * 8];
#pragma unroll
      for (int i = 0; i < 4; i++)
#pragma unroll
        for (int j = 0; j < 4; j++)
          acc[i][j] = __builtin_amdgcn_mfma_f32_16x16x32_bf16(af[i], bf[j], acc[i][j], 0, 0, 0);
    }
  }

  float gm = gamma[0];
#pragma unroll
  for (int i = 0; i < 4; i++) {
#pragma unroll
    for (int j = 0; j < 4; j++) {
#pragma unroll
      for (int r = 0; r < 4; r++) {
        int q = q0 + wm * 64 + i * 16 + g * 4 + r;
        int c = chan + wn * 64 + j * 16 + m;
        size_t row = (size_t)b * HW + q;
        float o = acc[i][j][r] * li[row];
        float xv = bf2f(xbT[row * CIN + c]);
        uT[row * CIN + c] = f2bf(gm * o + xv);
      }
    }
  }
}

// ---------------------------------------------------------------------------
extern "C" void kernel_launch(void* const* d_in, const int* in_sizes, int n_in,
                              void* d_out, int out_size, void* d_ws, size_t ws_size,
                              hipStream_t stream) {
  const float* x     = (const float*)d_in[0];
  const float* Wq    = (const float*)d_in[1];
  const float* bq    = (const float*)d_in[2];
  const float* Wk    = (const float*)d_in[3];
  const float* bk    = (const float*)d_in[4];
  const float* Wv    = (const float*)d_in[5];
  const float* bv    = (const float*)d_in[6];
  const float* gamma = (const float*)d_in[7];
  const float* Wd    = (const float*)d_in[8];
  const float* bd    = (const float*)d_in[9];

  char* ws = (char*)d_ws;
  size_t off = 0;
  auto alloc = [&](size_t bytes) {
    void* p = ws + off;
    off += (bytes + 255) & ~(size_t)255;
    return p;
  };
  u16*   xbT = (u16*)alloc((size_t)16384 * 512 * 2);
  u16*   qkT = (u16*)alloc((size_t)16384 * 128 * 2);
  u16*   vb  = (u16*)alloc((size_t)16384 * 512 * 2);
  u16*   uT  = (u16*)alloc((size_t)16384 * 512 * 2);
  u16*   wqk = (u16*)alloc((size_t)65536 * 2);
  u16*   wvb = (u16*)alloc((size_t)262144 * 2);
  u16*   wdb = (u16*)alloc((size_t)262144 * 2);
  float* bqk = (float*)alloc(128 * 4);
  float* li  = (float*)alloc((size_t)16384 * 4);
  size_t PB = (size_t)HW * HW * 2;
  int nb = 0;
  if      (off + 4 * PB <= ws_size) nb = 4;
  else if (off + 2 * PB <= ws_size) nb = 2;
  else if (off + 1 * PB <= ws_size) nb = 1;
  if (nb == 0) return;  // workspace too small -> poison stays -> loud failure
  u16* Pbuf = (u16*)alloc(nb * PB);

  cast_xT<<<dim3(64, 8, 4), 256, 0, stream>>>(x, xbT);
  cast_w<<<1024, 256, 0, stream>>>(Wq, Wk, Wv, Wd, bq, bk, wqk, wvb, wdb, bqk);
  // qkT (16384,128) = xbT * wqk^T
  gemm_bf16<<<dim3(1, 128), 256, 0, stream>>>(xbT, wqk, bqk, qkT, 16384, 128, 512, 0);
  // v (B,512,HW) = Wv * x
  gemm_bf16<<<dim3(128, 4), 256, 0, stream>>>(wvb, xbT, bv, vb, 512, 16384, 512, 1);
  // attention: P materialize + PV GEMM (staged by batch groups of nb)
  for (int b0 = 0; b0 < 4; b0 += nb) {
    ppass<<<dim3(nb * 128), 512, 0, stream>>>(qkT, Pbuf, li, b0);
    gemm_pv<<<dim3(4, 32, nb), 256, 0, stream>>>(Pbuf, vb, li, xbT, gamma, uT, b0);
  }
  // pam_out (B,512,HW) fp32 = Wd * u
  gemm_bf16<<<dim3(128, 4), 256, 0, stream>>>(wdb, uT, bd, d_out, 512, 16384, 512, 2);
}

// Round 17
// 192.854 us; speedup vs baseline: 1.2279x; 1.0036x over previous
//
#include <hip/hip_runtime.h>
#include <stdint.h>

#define HW   4096
#define CIN  512

typedef __attribute__((ext_vector_type(8))) short short8;
typedef __attribute__((ext_vector_type(4))) float f32x4;
typedef unsigned short u16;

#define GL16(src, ldsdst) __builtin_amdgcn_global_load_lds(                    \
    (const __attribute__((address_space(1))) void*)(src),                      \
    (__attribute__((address_space(3))) void*)(ldsdst), 16, 0, 0)

__device__ __forceinline__ u16 f2bf(float f) {
  union { float f; uint32_t u; } c; c.f = f;
  uint32_t r = (c.u + 0x7FFFu + ((c.u >> 16) & 1u)) >> 16;
  return (u16)r;
}
__device__ __forceinline__ float bf2f(u16 h) {
  union { uint32_t u; float f; } c; c.u = ((uint32_t)h) << 16;
  return c.f;
}

// ---------------------------------------------------------------------------
// x (B,C,HW) fp32  ->  xbT (B*HW, C) bf16   (64x64 tile transpose via LDS)
// ---------------------------------------------------------------------------
__global__ __launch_bounds__(256) void cast_xT(const float* __restrict__ x,
                                               u16* __restrict__ xbT) {
  __shared__ u16 t[64 * 72];
  int p0 = blockIdx.x * 64, c0 = blockIdx.y * 64, b = blockIdx.z;
  int tid = threadIdx.x, r = tid >> 2, ch = tid & 3;
  const float* xp = x + ((size_t)b * CIN + c0 + r) * HW + p0 + ch * 16;
  float4 f0 = *(const float4*)(xp + 0);
  float4 f1 = *(const float4*)(xp + 4);
  float4 f2 = *(const float4*)(xp + 8);
  float4 f3 = *(const float4*)(xp + 12);
  u16* tr = &t[r * 72 + ch * 16];
  tr[0] = f2bf(f0.x); tr[1] = f2bf(f0.y); tr[2] = f2bf(f0.z); tr[3] = f2bf(f0.w);
  tr[4] = f2bf(f1.x); tr[5] = f2bf(f1.y); tr[6] = f2bf(f1.z); tr[7] = f2bf(f1.w);
  tr[8] = f2bf(f2.x); tr[9] = f2bf(f2.y); tr[10] = f2bf(f2.z); tr[11] = f2bf(f2.w);
  tr[12] = f2bf(f3.x); tr[13] = f2bf(f3.y); tr[14] = f2bf(f3.z); tr[15] = f2bf(f3.w);
  __syncthreads();
  u16 o[16];
#pragma unroll
  for (int j = 0; j < 16; j++) o[j] = t[(ch * 16 + j) * 72 + r];
  u16* op = xbT + ((size_t)b * HW + p0 + r) * CIN + c0 + ch * 16;
  *(short8*)(op) = *(short8*)&o[0];
  *(short8*)(op + 8) = *(short8*)&o[8];
}

// ---------------------------------------------------------------------------
// weights -> bf16; wqk = [Wq*log2e; Wk] (128,512); bqk = [bq*log2e; bk]
// ---------------------------------------------------------------------------
__global__ void cast_w(const float* __restrict__ Wq, const float* __restrict__ Wk,
                       const float* __restrict__ Wv, const float* __restrict__ Wd,
                       const float* __restrict__ bq, const float* __restrict__ bk,
                       u16* __restrict__ wqk, u16* __restrict__ wv,
                       u16* __restrict__ wd, float* __restrict__ bqk) {
  const float LOG2E = 1.4426950408889634f;
  int i = blockIdx.x * 256 + threadIdx.x;
  if (i < 65536) wqk[i] = f2bf(i < 32768 ? Wq[i] * LOG2E : Wk[i - 32768]);
  if (i < 262144) { wv[i] = f2bf(Wv[i]); wd[i] = f2bf(Wd[i]); }
  if (i < 128) bqk[i] = (i < 64) ? bq[i] * LOG2E : bk[i - 64];
}

// ---------------------------------------------------------------------------
// Generic GEMM: C(M,N) = A(M,K) * BT(N,K)^T  (both bf16, K-contiguous rows)
// R16 K-unroll-4 structure. R17 change: bijective chunked XCD swizzle with
// m-tile FASTEST in wk -> the gridDim.y blocks sharing one BT panel are
// wk-adjacent -> same XCD -> panel fetched once into that XCD's L2
// (16 panels x 128KB + weights << 4MB). Requires total%8==0 (128/512 ok).
// ---------------------------------------------------------------------------
__global__ __launch_bounds__(256) void gemm_bf16(
    const u16* __restrict__ A, const u16* __restrict__ BT,
    const float* __restrict__ bias, void* __restrict__ out,
    int M, int N, int K, int mode) {
  __shared__ u16 la[4][128 * 32];
  __shared__ u16 lb[4][128 * 32];
  int tid = threadIdx.x;
  int w = tid >> 6, lane = tid & 63, m = lane & 15, g = lane >> 4;
  int wm = w >> 1, wn = w & 1;
  int nx = gridDim.x, ny = gridDim.y;
  int total = nx * ny;
  int hw = blockIdx.x + blockIdx.y * nx;           // HW dispatch order
  int wk = (hw & 7) * (total >> 3) + (hw >> 3);    // XCD-contiguous chunks
  int m0 = (wk % ny) * 128;                         // m-tile fastest
  int n0 = (wk / ny) * 128;
  int sr = lane >> 2, sc = (lane & 3) * 8;
  const u16* pa0 = A + (size_t)(m0 + w * 32 + sr) * K + sc;
  const u16* pa1 = pa0 + (size_t)16 * K;
  const u16* pb0 = BT + (size_t)(n0 + w * 32 + sr) * K + sc;
  const u16* pb1 = pb0 + (size_t)16 * K;

  f32x4 acc[4][4];
  f32x4 zero = {0.f, 0.f, 0.f, 0.f};
#pragma unroll
  for (int i = 0; i < 4; i++)
#pragma unroll
    for (int j = 0; j < 4; j++) acc[i][j] = zero;

  for (int k0 = 0; k0 < K; k0 += 128) {
    __syncthreads();
#pragma unroll
    for (int c = 0; c < 4; c++) {
      int kk = k0 + c * 32;
      GL16(pa0 + kk, &la[c][(w * 32) * 32]);
      GL16(pa1 + kk, &la[c][(w * 32 + 16) * 32]);
      GL16(pb0 + kk, &lb[c][(w * 32) * 32]);
      GL16(pb1 + kk, &lb[c][(w * 32 + 16) * 32]);
    }
    __syncthreads();
#pragma unroll
    for (int c = 0; c < 4; c++) {
      short8 af[4], bf[4];
#pragma unroll
      for (int i = 0; i < 4; i++)
        af[i] = *(const short8*)&la[c][(wm * 64 + i * 16 + m) * 32 + g * 8];
#pragma unroll
      for (int j = 0; j < 4; j++)
        bf[j] = *(const short8*)&lb[c][(wn * 64 + j * 16 + m) * 32 + g * 8];
#pragma unroll
      for (int i = 0; i < 4; i++)
#pragma unroll
        for (int j = 0; j < 4; j++)
          acc[i][j] = __builtin_amdgcn_mfma_f32_16x16x32_bf16(af[i], bf[j], acc[i][j], 0, 0, 0);
    }
  }

#pragma unroll
  for (int i = 0; i < 4; i++) {
#pragma unroll
    for (int j = 0; j < 4; j++) {
      int row_l = m0 + wm * 64 + i * 16 + g * 4;
      int col = n0 + wn * 64 + j * 16 + m;
#pragma unroll
      for (int r = 0; r < 4; r++) {
        int row = row_l + r;
        float v = acc[i][j][r];
        if (mode == 0) {
          v += bias[col];
          ((u16*)out)[(size_t)row * N + col] = f2bf(v);
        } else {
          v += bias[row];
          size_t addr = ((size_t)(col >> 12) * M + row) * HW + (col & (HW - 1));
          if (mode == 1) ((u16*)out)[addr] = f2bf(v);
          else           ((float*)out)[addr] = v;
        }
      }
    }
  }
}

// ---------------------------------------------------------------------------
// ppass: P = exp2(Q K^T) materialized bf16 + exact row-sum reciprocals.
// R16 structure (32 q-rows/block, 2 blocks/CU). R17 change: bijective
// chunked XCD swizzle -> each XCD's 64-block chunk covers ONE batch
// (its 4MB qkT = exactly one L2) -> K-panel staging reads are L2 hits.
// ---------------------------------------------------------------------------
__global__ __launch_bounds__(512) void ppass(
    const u16* __restrict__ qkT, u16* __restrict__ P,
    float* __restrict__ li, int b0) {
  __shared__ u16 kl[256 * 64];
  __shared__ float red[4][32];
  int tid = threadIdx.x;
  int w = tid >> 6, lane = tid & 63, m = lane & 15, g = lane >> 4;
  int total = gridDim.x;
  int hw = blockIdx.x;
  int wk = (hw & 7) * (total >> 3) + (hw >> 3);
  int bb = wk >> 7, b = b0 + bb;
  int q0 = (wk & 127) << 5;
  int qg = w & 1, jh = w >> 1;
  size_t qrow = (size_t)b * HW + q0;

  short8 aq[2];
#pragma unroll
  for (int ks = 0; ks < 2; ks++)
    aq[ks] = *(const short8*)(qkT + (qrow + qg * 16 + m) * 128 + ks * 32 + g * 8);

  float lr[4] = {0.f, 0.f, 0.f, 0.f};
  u16* Pb = P + ((size_t)bb * HW + q0) * HW;
  const u16* kb = qkT + (size_t)b * HW * 128 + 64;
  f32x4 zero = {0.f, 0.f, 0.f, 0.f};

  for (int jp = 0; jp < 16; jp++) {
    int j0 = jp * 256;
    __syncthreads();
#pragma unroll
    for (int it = 0; it < 4; it++) {
      int c = tid + it * 512;
      int row = c >> 3, seg = c & 7;
      short8 v = *(const short8*)(kb + (size_t)(j0 + row) * 128 + seg * 8);
      *(short8*)&kl[row * 64 + ((seg ^ (row & 7)) * 8)] = v;
    }
    __syncthreads();
#pragma unroll
    for (int jt = 0; jt < 4; jt++) {
      int jr = jh * 64 + jt * 16;
      int krow = jr + m;
      f32x4 s = zero;
#pragma unroll
      for (int ks = 0; ks < 2; ks++) {
        short8 bk = *(const short8*)&kl[krow * 64 + (((ks * 4 + g) ^ (krow & 7)) * 8)];
        s = __builtin_amdgcn_mfma_f32_16x16x32_bf16(aq[ks], bk, s, 0, 0, 0);
      }
      int j = j0 + jr + m;
#pragma unroll
      for (int r = 0; r < 4; r++) {
        float p = exp2f(s[r]);
        lr[r] += p;
        Pb[(size_t)(qg * 16 + g * 4 + r) * HW + j] = f2bf(p);
      }
    }
  }
#pragma unroll
  for (int r = 0; r < 4; r++) {
#pragma unroll
    for (int off = 1; off < 16; off <<= 1)
      lr[r] += __shfl_xor(lr[r], off);
  }
  __syncthreads();
  if (m == 0) {
#pragma unroll
    for (int r = 0; r < 4; r++) red[jh][qg * 16 + g * 4 + r] = lr[r];
  }
  __syncthreads();
  if (tid < 32)
    li[qrow + tid] = 1.0f / (red[0][tid] + red[1][tid] + red[2][tid] + red[3][tid]);
}

// ---------------------------------------------------------------------------
// gemm_pv: uT = gamma * (P * V^T) .* li + xbT.
// (unchanged - proven R15/R16: 128x128 tile, K-unroll-4, chunked XCD swizzle)
// ---------------------------------------------------------------------------
__global__ __launch_bounds__(256) void gemm_pv(
    const u16* __restrict__ P, const u16* __restrict__ V,
    const float* __restrict__ li, const u16* __restrict__ xbT,
    const float* __restrict__ gamma, u16* __restrict__ uT, int b0) {
  __shared__ u16 la[4][128 * 32];
  __shared__ u16 lb[4][128 * 32];
  int tid = threadIdx.x;
  int w = tid >> 6, lane = tid & 63, m = lane & 15, g = lane >> 4;
  int wm = w >> 1, wn = w & 1;
  int total = gridDim.x * gridDim.y * gridDim.z;
  int lid = blockIdx.x + (blockIdx.y << 2) + (blockIdx.z << 7);
  int wk = (lid & 7) * (total >> 3) + (lid >> 3);
  int chan = (wk & 3) << 7;          // channel quarter: 0,128,256,384
  int q0 = ((wk >> 2) & 31) << 7;    // q-tile of 128
  int bb = wk >> 7, b = b0 + bb;
  int sr = lane >> 2, sc = (lane & 3) * 8;

  const u16* pa0 = P + ((size_t)bb * HW + q0 + w * 32 + sr) * HW + sc;
  const u16* pa1 = pa0 + (size_t)16 * HW;
  const u16* pb0 = V + ((size_t)b * CIN + chan + w * 32 + sr) * HW + sc;
  const u16* pb1 = pb0 + (size_t)16 * HW;

  f32x4 acc[4][4];
  f32x4 zero = {0.f, 0.f, 0.f, 0.f};
#pragma unroll
  for (int i = 0; i < 4; i++)
#pragma unroll
    for (int j = 0; j < 4; j++) acc[i][j] = zero;

  for (int k0 = 0; k0 < HW; k0 += 128) {
    __syncthreads();
#pragma unroll
    for (int c = 0; c < 4; c++) {
      int kk = k0 + c * 32;
      GL16(pa0 + kk, &la[c][(w * 32) * 32]);
      GL16(pa1 + kk, &la[c][(w * 32 + 16) * 32]);
      GL16(pb0 + kk, &lb[c][(w * 32) * 32]);
      GL16(pb1 + kk, &lb[c][(w * 32 + 16) * 32]);
    }
    __syncthreads();
#pragma unroll
    for (int c = 0; c < 4; c++) {
      short8 af[4], bf[4];
#pragma unroll
      for (int i = 0; i < 4; i++)
        af[i] = *(const short8*)&la[c][(wm * 64 + i * 16 + m) * 32 + g * 8];
#pragma unroll
      for (int j = 0; j < 4; j++)
        bf[j] = *(const short8*)&lb[c][(wn * 64 + j * 16 + m) * 32 + g * 8];
#pragma unroll
      for (int i = 0; i < 4; i++)
#pragma unroll
        for (int j = 0; j < 4; j++)
          acc[i][j] = __builtin_amdgcn_mfma_f32_16x16x32_bf16(af[i], bf[j], acc[i][j], 0, 0, 0);
    }
  }

  float gm = gamma[0];
#pragma unroll
  for (int i = 0; i < 4; i++) {
#pragma unroll
    for (int j = 0; j < 4; j++) {
#pragma unroll
      for (int r = 0; r < 4; r++) {
        int q = q0 + wm * 64 + i * 16 + g * 4 + r;
        int c = chan + wn * 64 + j * 16 + m;
        size_t row = (size_t)b * HW + q;
        float o = acc[i][j][r] * li[row];
        float xv = bf2f(xbT[row * CIN + c]);
        uT[row * CIN + c] = f2bf(gm * o + xv);
      }
    }
  }
}

// ---------------------------------------------------------------------------
extern "C" void kernel_launch(void* const* d_in, const int* in_sizes, int n_in,
                              void* d_out, int out_size, void* d_ws, size_t ws_size,
                              hipStream_t stream) {
  const float* x     = (const float*)d_in[0];
  const float* Wq    = (const float*)d_in[1];
  const float* bq    = (const float*)d_in[2];
  const float* Wk    = (const float*)d_in[3];
  const float* bk    = (const float*)d_in[4];
  const float* Wv    = (const float*)d_in[5];
  const float* bv    = (const float*)d_in[6];
  const float* gamma = (const float*)d_in[7];
  const float* Wd    = (const float*)d_in[8];
  const float* bd    = (const float*)d_in[9];

  char* ws = (char*)d_ws;
  size_t off = 0;
  auto alloc = [&](size_t bytes) {
    void* p = ws + off;
    off += (bytes + 255) & ~(size_t)255;
    return p;
  };
  u16*   xbT = (u16*)alloc((size_t)16384 * 512 * 2);
  u16*   qkT = (u16*)alloc((size_t)16384 * 128 * 2);
  u16*   vb  = (u16*)alloc((size_t)16384 * 512 * 2);
  u16*   uT  = (u16*)alloc((size_t)16384 * 512 * 2);
  u16*   wqk = (u16*)alloc((size_t)65536 * 2);
  u16*   wvb = (u16*)alloc((size_t)262144 * 2);
  u16*   wdb = (u16*)alloc((size_t)262144 * 2);
  float* bqk = (float*)alloc(128 * 4);
  float* li  = (float*)alloc((size_t)16384 * 4);
  size_t PB = (size_t)HW * HW * 2;
  int nb = 0;
  if      (off + 4 * PB <= ws_size) nb = 4;
  else if (off + 2 * PB <= ws_size) nb = 2;
  else if (off + 1 * PB <= ws_size) nb = 1;
  if (nb == 0) return;  // workspace too small -> poison stays -> loud failure
  u16* Pbuf = (u16*)alloc(nb * PB);

  cast_xT<<<dim3(64, 8, 4), 256, 0, stream>>>(x, xbT);
  cast_w<<<1024, 256, 0, stream>>>(Wq, Wk, Wv, Wd, bq, bk, wqk, wvb, wdb, bqk);
  // qkT (16384,128) = xbT * wqk^T
  gemm_bf16<<<dim3(1, 128), 256, 0, stream>>>(xbT, wqk, bqk, qkT, 16384, 128, 512, 0);
  // v (B,512,HW) = Wv * x
  gemm_bf16<<<dim3(128, 4), 256, 0, stream>>>(wvb, xbT, bv, vb, 512, 16384, 512, 1);
  // attention: P materialize + PV GEMM (staged by batch groups of nb)
  for (int b0 = 0; b0 < 4; b0 += nb) {
    ppass<<<dim3(nb * 128), 512, 0, stream>>>(qkT, Pbuf, li, b0);
    gemm_pv<<<dim3(4, 32, nb), 256, 0, stream>>>(Pbuf, vb, li, xbT, gamma, uT, b0);
  }
  // pam_out (B,512,HW) fp32 = Wd * u
  gemm_bf16<<<dim3(128, 4), 256, 0, stream>>>(wdb, uT, bd, d_out, 512, 16384, 512, 2);
}

// Round 18
// 189.395 us; speedup vs baseline: 1.2504x; 1.0183x over previous
//
#include <hip/hip_runtime.h>
#include <stdint.h>

#define HW   4096
#define CIN  512

typedef __attribute__((ext_vector_type(8))) short short8;
typedef __attribute__((ext_vector_type(4))) float f32x4;
typedef unsigned short u16;

#define GL16(src, ldsdst) __builtin_amdgcn_global_load_lds(                    \
    (const __attribute__((address_space(1))) void*)(src),                      \
    (__attribute__((address_space(3))) void*)(ldsdst), 16, 0, 0)

__device__ __forceinline__ u16 f2bf(float f) {
  union { float f; uint32_t u; } c; c.f = f;
  uint32_t r = (c.u + 0x7FFFu + ((c.u >> 16) & 1u)) >> 16;
  return (u16)r;
}
__device__ __forceinline__ float bf2f(u16 h) {
  union { uint32_t u; float f; } c; c.u = ((uint32_t)h) << 16;
  return c.f;
}

// ---------------------------------------------------------------------------
// x (B,C,HW) fp32  ->  xbT (B*HW, C) bf16   (64x64 tile transpose via LDS)
// ---------------------------------------------------------------------------
__global__ __launch_bounds__(256) void cast_xT(const float* __restrict__ x,
                                               u16* __restrict__ xbT) {
  __shared__ u16 t[64 * 72];
  int p0 = blockIdx.x * 64, c0 = blockIdx.y * 64, b = blockIdx.z;
  int tid = threadIdx.x, r = tid >> 2, ch = tid & 3;
  const float* xp = x + ((size_t)b * CIN + c0 + r) * HW + p0 + ch * 16;
  float4 f0 = *(const float4*)(xp + 0);
  float4 f1 = *(const float4*)(xp + 4);
  float4 f2 = *(const float4*)(xp + 8);
  float4 f3 = *(const float4*)(xp + 12);
  u16* tr = &t[r * 72 + ch * 16];
  tr[0] = f2bf(f0.x); tr[1] = f2bf(f0.y); tr[2] = f2bf(f0.z); tr[3] = f2bf(f0.w);
  tr[4] = f2bf(f1.x); tr[5] = f2bf(f1.y); tr[6] = f2bf(f1.z); tr[7] = f2bf(f1.w);
  tr[8] = f2bf(f2.x); tr[9] = f2bf(f2.y); tr[10] = f2bf(f2.z); tr[11] = f2bf(f2.w);
  tr[12] = f2bf(f3.x); tr[13] = f2bf(f3.y); tr[14] = f2bf(f3.z); tr[15] = f2bf(f3.w);
  __syncthreads();
  u16 o[16];
#pragma unroll
  for (int j = 0; j < 16; j++) o[j] = t[(ch * 16 + j) * 72 + r];
  u16* op = xbT + ((size_t)b * HW + p0 + r) * CIN + c0 + ch * 16;
  *(short8*)(op) = *(short8*)&o[0];
  *(short8*)(op + 8) = *(short8*)&o[8];
}

// ---------------------------------------------------------------------------
// weights -> bf16; wqk = [Wq*log2e; Wk] (128,512); bqk = [bq*log2e; bk]
// ---------------------------------------------------------------------------
__global__ void cast_w(const float* __restrict__ Wq, const float* __restrict__ Wk,
                       const float* __restrict__ Wv, const float* __restrict__ Wd,
                       const float* __restrict__ bq, const float* __restrict__ bk,
                       u16* __restrict__ wqk, u16* __restrict__ wv,
                       u16* __restrict__ wd, float* __restrict__ bqk) {
  const float LOG2E = 1.4426950408889634f;
  int i = blockIdx.x * 256 + threadIdx.x;
  if (i < 65536) wqk[i] = f2bf(i < 32768 ? Wq[i] * LOG2E : Wk[i - 32768]);
  if (i < 262144) { wv[i] = f2bf(Wv[i]); wd[i] = f2bf(Wd[i]); }
  if (i < 128) bqk[i] = (i < 64) ? bq[i] * LOG2E : bk[i - 64];
}

// ---------------------------------------------------------------------------
// Generic GEMM: C(M,N) = A(M,K) * BT(N,K)^T  (both bf16, K-contiguous rows)
// (unchanged from R17 - K-unroll-4, chunked XCD swizzle, m-tile fastest)
// ---------------------------------------------------------------------------
__global__ __launch_bounds__(256) void gemm_bf16(
    const u16* __restrict__ A, const u16* __restrict__ BT,
    const float* __restrict__ bias, void* __restrict__ out,
    int M, int N, int K, int mode) {
  __shared__ u16 la[4][128 * 32];
  __shared__ u16 lb[4][128 * 32];
  int tid = threadIdx.x;
  int w = tid >> 6, lane = tid & 63, m = lane & 15, g = lane >> 4;
  int wm = w >> 1, wn = w & 1;
  int nx = gridDim.x, ny = gridDim.y;
  int total = nx * ny;
  int hw = blockIdx.x + blockIdx.y * nx;           // HW dispatch order
  int wk = (hw & 7) * (total >> 3) + (hw >> 3);    // XCD-contiguous chunks
  int m0 = (wk % ny) * 128;                         // m-tile fastest
  int n0 = (wk / ny) * 128;
  int sr = lane >> 2, sc = (lane & 3) * 8;
  const u16* pa0 = A + (size_t)(m0 + w * 32 + sr) * K + sc;
  const u16* pa1 = pa0 + (size_t)16 * K;
  const u16* pb0 = BT + (size_t)(n0 + w * 32 + sr) * K + sc;
  const u16* pb1 = pb0 + (size_t)16 * K;

  f32x4 acc[4][4];
  f32x4 zero = {0.f, 0.f, 0.f, 0.f};
#pragma unroll
  for (int i = 0; i < 4; i++)
#pragma unroll
    for (int j = 0; j < 4; j++) acc[i][j] = zero;

  for (int k0 = 0; k0 < K; k0 += 128) {
    __syncthreads();
#pragma unroll
    for (int c = 0; c < 4; c++) {
      int kk = k0 + c * 32;
      GL16(pa0 + kk, &la[c][(w * 32) * 32]);
      GL16(pa1 + kk, &la[c][(w * 32 + 16) * 32]);
      GL16(pb0 + kk, &lb[c][(w * 32) * 32]);
      GL16(pb1 + kk, &lb[c][(w * 32 + 16) * 32]);
    }
    __syncthreads();
#pragma unroll
    for (int c = 0; c < 4; c++) {
      short8 af[4], bf[4];
#pragma unroll
      for (int i = 0; i < 4; i++)
        af[i] = *(const short8*)&la[c][(wm * 64 + i * 16 + m) * 32 + g * 8];
#pragma unroll
      for (int j = 0; j < 4; j++)
        bf[j] = *(const short8*)&lb[c][(wn * 64 + j * 16 + m) * 32 + g * 8];
#pragma unroll
      for (int i = 0; i < 4; i++)
#pragma unroll
        for (int j = 0; j < 4; j++)
          acc[i][j] = __builtin_amdgcn_mfma_f32_16x16x32_bf16(af[i], bf[j], acc[i][j], 0, 0, 0);
    }
  }

#pragma unroll
  for (int i = 0; i < 4; i++) {
#pragma unroll
    for (int j = 0; j < 4; j++) {
      int row_l = m0 + wm * 64 + i * 16 + g * 4;
      int col = n0 + wn * 64 + j * 16 + m;
#pragma unroll
      for (int r = 0; r < 4; r++) {
        int row = row_l + r;
        float v = acc[i][j][r];
        if (mode == 0) {
          v += bias[col];
          ((u16*)out)[(size_t)row * N + col] = f2bf(v);
        } else {
          v += bias[row];
          size_t addr = ((size_t)(col >> 12) * M + row) * HW + (col & (HW - 1));
          if (mode == 1) ((u16*)out)[addr] = f2bf(v);
          else           ((float*)out)[addr] = v;
        }
      }
    }
  }
}

// ---------------------------------------------------------------------------
// ppass: P = exp2(Q K^T) materialized bf16 + exact row-sum reciprocals.
// R18 change (T14 async-stage split): K-panel staging is reg-staged
// (load -> ds_write), so next panel's global loads are issued into
// REGISTERS right after this panel's kl writes -- their L2 latency hides
// under this panel's compute. Registers are private (race-free); ds_write
// still occurs after the barrier protecting kl. All else identical to R17.
// ---------------------------------------------------------------------------
__global__ __launch_bounds__(512) void ppass(
    const u16* __restrict__ qkT, u16* __restrict__ P,
    float* __restrict__ li, int b0) {
  __shared__ u16 kl[256 * 64];
  __shared__ float red[4][32];
  int tid = threadIdx.x;
  int w = tid >> 6, lane = tid & 63, m = lane & 15, g = lane >> 4;
  int total = gridDim.x;
  int hw = blockIdx.x;
  int wk = (hw & 7) * (total >> 3) + (hw >> 3);
  int bb = wk >> 7, b = b0 + bb;
  int q0 = (wk & 127) << 5;
  int qg = w & 1, jh = w >> 1;
  size_t qrow = (size_t)b * HW + q0;

  short8 aq[2];
#pragma unroll
  for (int ks = 0; ks < 2; ks++)
    aq[ks] = *(const short8*)(qkT + (qrow + qg * 16 + m) * 128 + ks * 32 + g * 8);

  float lr[4] = {0.f, 0.f, 0.f, 0.f};
  u16* Pb = P + ((size_t)bb * HW + q0) * HW;
  const u16* kb = qkT + (size_t)b * HW * 128 + 64;
  f32x4 zero = {0.f, 0.f, 0.f, 0.f};

  int prow = tid >> 3, pseg = tid & 7;             // this thread's panel slot
  const u16* psrc = kb + (size_t)prow * 128 + pseg * 8;
  int pdst = prow * 64 + ((pseg ^ (prow & 7)) * 8);

  // prefetch panel 0 into registers
  short8 pf[4];
#pragma unroll
  for (int it = 0; it < 4; it++)
    pf[it] = *(const short8*)(psrc + (size_t)(it * 64) * 128);

  for (int jp = 0; jp < 16; jp++) {
    int j0 = jp * 256;
    __syncthreads();                 // previous compute done reading kl
#pragma unroll
    for (int it = 0; it < 4; it++)
      *(short8*)&kl[pdst + it * 64 * 64] = pf[it];
    if (jp < 15) {                   // issue next panel's loads (hide L2 lat)
#pragma unroll
      for (int it = 0; it < 4; it++)
        pf[it] = *(const short8*)(psrc + (size_t)(j0 + 256 + it * 64) * 128);
    }
    __syncthreads();                 // kl ready
#pragma unroll
    for (int jt = 0; jt < 4; jt++) {
      int jr = jh * 64 + jt * 16;
      int krow = jr + m;
      f32x4 s = zero;
#pragma unroll
      for (int ks = 0; ks < 2; ks++) {
        short8 bk = *(const short8*)&kl[krow * 64 + (((ks * 4 + g) ^ (krow & 7)) * 8)];
        s = __builtin_amdgcn_mfma_f32_16x16x32_bf16(aq[ks], bk, s, 0, 0, 0);
      }
      int j = j0 + jr + m;
#pragma unroll
      for (int r = 0; r < 4; r++) {
        float p = exp2f(s[r]);
        lr[r] += p;
        Pb[(size_t)(qg * 16 + g * 4 + r) * HW + j] = f2bf(p);
      }
    }
  }
#pragma unroll
  for (int r = 0; r < 4; r++) {
#pragma unroll
    for (int off = 1; off < 16; off <<= 1)
      lr[r] += __shfl_xor(lr[r], off);
  }
  __syncthreads();
  if (m == 0) {
#pragma unroll
    for (int r = 0; r < 4; r++) red[jh][qg * 16 + g * 4 + r] = lr[r];
  }
  __syncthreads();
  if (tid < 32)
    li[qrow + tid] = 1.0f / (red[0][tid] + red[1][tid] + red[2][tid] + red[3][tid]);
}

// ---------------------------------------------------------------------------
// gemm_pv: uT = gamma * (P * V^T) .* li + xbT.
// (unchanged - proven R15/R16/R17: 128x128 tile, K-unroll-4, XCD swizzle)
// ---------------------------------------------------------------------------
__global__ __launch_bounds__(256) void gemm_pv(
    const u16* __restrict__ P, const u16* __restrict__ V,
    const float* __restrict__ li, const u16* __restrict__ xbT,
    const float* __restrict__ gamma, u16* __restrict__ uT, int b0) {
  __shared__ u16 la[4][128 * 32];
  __shared__ u16 lb[4][128 * 32];
  int tid = threadIdx.x;
  int w = tid >> 6, lane = tid & 63, m = lane & 15, g = lane >> 4;
  int wm = w >> 1, wn = w & 1;
  int total = gridDim.x * gridDim.y * gridDim.z;
  int lid = blockIdx.x + (blockIdx.y << 2) + (blockIdx.z << 7);
  int wk = (lid & 7) * (total >> 3) + (lid >> 3);
  int chan = (wk & 3) << 7;          // channel quarter: 0,128,256,384
  int q0 = ((wk >> 2) & 31) << 7;    // q-tile of 128
  int bb = wk >> 7, b = b0 + bb;
  int sr = lane >> 2, sc = (lane & 3) * 8;

  const u16* pa0 = P + ((size_t)bb * HW + q0 + w * 32 + sr) * HW + sc;
  const u16* pa1 = pa0 + (size_t)16 * HW;
  const u16* pb0 = V + ((size_t)b * CIN + chan + w * 32 + sr) * HW + sc;
  const u16* pb1 = pb0 + (size_t)16 * HW;

  f32x4 acc[4][4];
  f32x4 zero = {0.f, 0.f, 0.f, 0.f};
#pragma unroll
  for (int i = 0; i < 4; i++)
#pragma unroll
    for (int j = 0; j < 4; j++) acc[i][j] = zero;

  for (int k0 = 0; k0 < HW; k0 += 128) {
    __syncthreads();
#pragma unroll
    for (int c = 0; c < 4; c++) {
      int kk = k0 + c * 32;
      GL16(pa0 + kk, &la[c][(w * 32) * 32]);
      GL16(pa1 + kk, &la[c][(w * 32 + 16) * 32]);
      GL16(pb0 + kk, &lb[c][(w * 32) * 32]);
      GL16(pb1 + kk, &lb[c][(w * 32 + 16) * 32]);
    }
    __syncthreads();
#pragma unroll
    for (int c = 0; c < 4; c++) {
      short8 af[4], bf[4];
#pragma unroll
      for (int i = 0; i < 4; i++)
        af[i] = *(const short8*)&la[c][(wm * 64 + i * 16 + m) * 32 + g * 8];
#pragma unroll
      for (int j = 0; j < 4; j++)
        bf[j] = *(const short8*)&lb[c][(wn * 64 + j * 16 + m) * 32 + g * 8];
#pragma unroll
      for (int i = 0; i < 4; i++)
#pragma unroll
        for (int j = 0; j < 4; j++)
          acc[i][j] = __builtin_amdgcn_mfma_f32_16x16x32_bf16(af[i], bf[j], acc[i][j], 0, 0, 0);
    }
  }

  float gm = gamma[0];
#pragma unroll
  for (int i = 0; i < 4; i++) {
#pragma unroll
    for (int j = 0; j < 4; j++) {
#pragma unroll
      for (int r = 0; r < 4; r++) {
        int q = q0 + wm * 64 + i * 16 + g * 4 + r;
        int c = chan + wn * 64 + j * 16 + m;
        size_t row = (size_t)b * HW + q;
        float o = acc[i][j][r] * li[row];
        float xv = bf2f(xbT[row * CIN + c]);
        uT[row * CIN + c] = f2bf(gm * o + xv);
      }
    }
  }
}

// ---------------------------------------------------------------------------
extern "C" void kernel_launch(void* const* d_in, const int* in_sizes, int n_in,
                              void* d_out, int out_size, void* d_ws, size_t ws_size,
                              hipStream_t stream) {
  const float* x     = (const float*)d_in[0];
  const float* Wq    = (const float*)d_in[1];
  const float* bq    = (const float*)d_in[2];
  const float* Wk    = (const float*)d_in[3];
  const float* bk    = (const float*)d_in[4];
  const float* Wv    = (const float*)d_in[5];
  const float* bv    = (const float*)d_in[6];
  const float* gamma = (const float*)d_in[7];
  const float* Wd    = (const float*)d_in[8];
  const float* bd    = (const float*)d_in[9];

  char* ws = (char*)d_ws;
  size_t off = 0;
  auto alloc = [&](size_t bytes) {
    void* p = ws + off;
    off += (bytes + 255) & ~(size_t)255;
    return p;
  };
  u16*   xbT = (u16*)alloc((size_t)16384 * 512 * 2);
  u16*   qkT = (u16*)alloc((size_t)16384 * 128 * 2);
  u16*   vb  = (u16*)alloc((size_t)16384 * 512 * 2);
  u16*   uT  = (u16*)alloc((size_t)16384 * 512 * 2);
  u16*   wqk = (u16*)alloc((size_t)65536 * 2);
  u16*   wvb = (u16*)alloc((size_t)262144 * 2);
  u16*   wdb = (u16*)alloc((size_t)262144 * 2);
  float* bqk = (float*)alloc(128 * 4);
  float* li  = (float*)alloc((size_t)16384 * 4);
  size_t PB = (size_t)HW * HW * 2;
  int nb = 0;
  if      (off + 4 * PB <= ws_size) nb = 4;
  else if (off + 2 * PB <= ws_size) nb = 2;
  else if (off + 1 * PB <= ws_size) nb = 1;
  if (nb == 0) return;  // workspace too small -> poison stays -> loud failure
  u16* Pbuf = (u16*)alloc(nb * PB);

  cast_xT<<<dim3(64, 8, 4), 256, 0, stream>>>(x, xbT);
  cast_w<<<1024, 256, 0, stream>>>(Wq, Wk, Wv, Wd, bq, bk, wqk, wvb, wdb, bqk);
  // qkT (16384,128) = xbT * wqk^T
  gemm_bf16<<<dim3(1, 128), 256, 0, stream>>>(xbT, wqk, bqk, qkT, 16384, 128, 512, 0);
  // v (B,512,HW) = Wv * x
  gemm_bf16<<<dim3(128, 4), 256, 0, stream>>>(wvb, xbT, bv, vb, 512, 16384, 512, 1);
  // attention: P materialize + PV GEMM (staged by batch groups of nb)
  for (int b0 = 0; b0 < 4; b0 += nb) {
    ppass<<<dim3(nb * 128), 512, 0, stream>>>(qkT, Pbuf, li, b0);
    gemm_pv<<<dim3(4, 32, nb), 256, 0, stream>>>(Pbuf, vb, li, xbT, gamma, uT, b0);
  }
  // pam_out (B,512,HW) fp32 = Wd * u
  gemm_bf16<<<dim3(128, 4), 256, 0, stream>>>(wdb, uT, bd, d_out, 512, 16384, 512, 2);
}

// Round 19
// 181.151 us; speedup vs baseline: 1.3073x; 1.0455x over previous
//
#include <hip/hip_runtime.h>
#include <stdint.h>

#define HW   4096
#define CIN  512

typedef __attribute__((ext_vector_type(8))) short short8;
typedef __attribute__((ext_vector_type(4))) float f32x4;
typedef unsigned short u16;

#define GL16(src, ldsdst) __builtin_amdgcn_global_load_lds(                    \
    (const __attribute__((address_space(1))) void*)(src),                      \
    (__attribute__((address_space(3))) void*)(ldsdst), 16, 0, 0)

__device__ __forceinline__ u16 f2bf(float f) {
  union { float f; uint32_t u; } c; c.f = f;
  uint32_t r = (c.u + 0x7FFFu + ((c.u >> 16) & 1u)) >> 16;
  return (u16)r;
}
__device__ __forceinline__ float bf2f(u16 h) {
  union { uint32_t u; float f; } c; c.u = ((uint32_t)h) << 16;
  return c.f;
}

// ---------------------------------------------------------------------------
// x (B,C,HW) fp32  ->  xbT (B*HW, C) bf16   (64x64 tile transpose via LDS)
// ---------------------------------------------------------------------------
__global__ __launch_bounds__(256) void cast_xT(const float* __restrict__ x,
                                               u16* __restrict__ xbT) {
  __shared__ u16 t[64 * 72];
  int p0 = blockIdx.x * 64, c0 = blockIdx.y * 64, b = blockIdx.z;
  int tid = threadIdx.x, r = tid >> 2, ch = tid & 3;
  const float* xp = x + ((size_t)b * CIN + c0 + r) * HW + p0 + ch * 16;
  float4 f0 = *(const float4*)(xp + 0);
  float4 f1 = *(const float4*)(xp + 4);
  float4 f2 = *(const float4*)(xp + 8);
  float4 f3 = *(const float4*)(xp + 12);
  u16* tr = &t[r * 72 + ch * 16];
  tr[0] = f2bf(f0.x); tr[1] = f2bf(f0.y); tr[2] = f2bf(f0.z); tr[3] = f2bf(f0.w);
  tr[4] = f2bf(f1.x); tr[5] = f2bf(f1.y); tr[6] = f2bf(f1.z); tr[7] = f2bf(f1.w);
  tr[8] = f2bf(f2.x); tr[9] = f2bf(f2.y); tr[10] = f2bf(f2.z); tr[11] = f2bf(f2.w);
  tr[12] = f2bf(f3.x); tr[13] = f2bf(f3.y); tr[14] = f2bf(f3.z); tr[15] = f2bf(f3.w);
  __syncthreads();
  u16 o[16];
#pragma unroll
  for (int j = 0; j < 16; j++) o[j] = t[(ch * 16 + j) * 72 + r];
  u16* op = xbT + ((size_t)b * HW + p0 + r) * CIN + c0 + ch * 16;
  *(short8*)(op) = *(short8*)&o[0];
  *(short8*)(op + 8) = *(short8*)&o[8];
}

// ---------------------------------------------------------------------------
// weights -> bf16; wqk = [Wq*log2e; Wk] (128,512); bqk = [bq*log2e; bk]
// ---------------------------------------------------------------------------
__global__ void cast_w(const float* __restrict__ Wq, const float* __restrict__ Wk,
                       const float* __restrict__ Wv, const float* __restrict__ Wd,
                       const float* __restrict__ bq, const float* __restrict__ bk,
                       u16* __restrict__ wqk, u16* __restrict__ wv,
                       u16* __restrict__ wd, float* __restrict__ bqk) {
  const float LOG2E = 1.4426950408889634f;
  int i = blockIdx.x * 256 + threadIdx.x;
  if (i < 65536) wqk[i] = f2bf(i < 32768 ? Wq[i] * LOG2E : Wk[i - 32768]);
  if (i < 262144) { wv[i] = f2bf(Wv[i]); wd[i] = f2bf(Wd[i]); }
  if (i < 128) bqk[i] = (i < 64) ? bq[i] * LOG2E : bk[i - 64];
}

// ---------------------------------------------------------------------------
// qk_gemm: qkT(16384,128) = xbT(16384,512) x wqk(128,512)^T + bqk.
// Dedicated small-N GEMM: 64-row x 128-col tile, 4 waves (2x2, wave 32x64
// = 2x4 frags), K=512, unroll-2 (R12-proven pattern), 24 KB LDS.
// Grid 256 blocks (2x the old 128) -> 1 block/CU. wqk (128 KB) L2-hits.
// ---------------------------------------------------------------------------
__global__ __launch_bounds__(256) void qk_gemm(
    const u16* __restrict__ xbT, const u16* __restrict__ wqk,
    const float* __restrict__ bqk, u16* __restrict__ qkT) {
  __shared__ u16 la[2][64 * 32];
  __shared__ u16 lb[2][128 * 32];
  int tid = threadIdx.x;
  int w = tid >> 6, lane = tid & 63, m = lane & 15, g = lane >> 4;
  int wm = w >> 1, wn = w & 1;
  int hw = blockIdx.x;
  int wk = (hw & 7) * (gridDim.x >> 3) + (hw >> 3);   // XCD-contiguous
  int q0 = wk << 6;
  int sr = lane >> 2, sc = (lane & 3) * 8;

  const u16* pa  = xbT + (size_t)(q0 + w * 16 + sr) * CIN + sc;
  const u16* pb0 = wqk + (size_t)(w * 32 + sr) * CIN + sc;
  const u16* pb1 = pb0 + (size_t)16 * CIN;

  f32x4 acc[2][4];
  f32x4 zero = {0.f, 0.f, 0.f, 0.f};
#pragma unroll
  for (int i = 0; i < 2; i++)
#pragma unroll
    for (int j = 0; j < 4; j++) acc[i][j] = zero;

  for (int k0 = 0; k0 < CIN; k0 += 64) {
    __syncthreads();
#pragma unroll
    for (int c = 0; c < 2; c++) {
      int kk = k0 + c * 32;
      GL16(pa + kk,  &la[c][(w * 16) * 32]);
      GL16(pb0 + kk, &lb[c][(w * 32) * 32]);
      GL16(pb1 + kk, &lb[c][(w * 32 + 16) * 32]);
    }
    __syncthreads();
#pragma unroll
    for (int c = 0; c < 2; c++) {
      short8 af[2], bf[4];
#pragma unroll
      for (int i = 0; i < 2; i++)
        af[i] = *(const short8*)&la[c][(wm * 32 + i * 16 + m) * 32 + g * 8];
#pragma unroll
      for (int j = 0; j < 4; j++)
        bf[j] = *(const short8*)&lb[c][(wn * 64 + j * 16 + m) * 32 + g * 8];
#pragma unroll
      for (int i = 0; i < 2; i++)
#pragma unroll
        for (int j = 0; j < 4; j++)
          acc[i][j] = __builtin_amdgcn_mfma_f32_16x16x32_bf16(af[i], bf[j], acc[i][j], 0, 0, 0);
    }
  }

#pragma unroll
  for (int i = 0; i < 2; i++) {
#pragma unroll
    for (int j = 0; j < 4; j++) {
#pragma unroll
      for (int r = 0; r < 4; r++) {
        int q = q0 + wm * 32 + i * 16 + g * 4 + r;
        int c = wn * 64 + j * 16 + m;
        qkT[(size_t)q * 128 + c] = f2bf(acc[i][j][r] + bqk[c]);
      }
    }
  }
}

// ---------------------------------------------------------------------------
// Generic GEMM: C(M,N) = A(M,K) * BT(N,K)^T  (both bf16, K-contiguous rows)
// (unchanged from R17/R18 - K-unroll-4, chunked XCD swizzle, m-tile fastest)
// ---------------------------------------------------------------------------
__global__ __launch_bounds__(256) void gemm_bf16(
    const u16* __restrict__ A, const u16* __restrict__ BT,
    const float* __restrict__ bias, void* __restrict__ out,
    int M, int N, int K, int mode) {
  __shared__ u16 la[4][128 * 32];
  __shared__ u16 lb[4][128 * 32];
  int tid = threadIdx.x;
  int w = tid >> 6, lane = tid & 63, m = lane & 15, g = lane >> 4;
  int wm = w >> 1, wn = w & 1;
  int nx = gridDim.x, ny = gridDim.y;
  int total = nx * ny;
  int hw = blockIdx.x + blockIdx.y * nx;           // HW dispatch order
  int wk = (hw & 7) * (total >> 3) + (hw >> 3);    // XCD-contiguous chunks
  int m0 = (wk % ny) * 128;                         // m-tile fastest
  int n0 = (wk / ny) * 128;
  int sr = lane >> 2, sc = (lane & 3) * 8;
  const u16* pa0 = A + (size_t)(m0 + w * 32 + sr) * K + sc;
  const u16* pa1 = pa0 + (size_t)16 * K;
  const u16* pb0 = BT + (size_t)(n0 + w * 32 + sr) * K + sc;
  const u16* pb1 = pb0 + (size_t)16 * K;

  f32x4 acc[4][4];
  f32x4 zero = {0.f, 0.f, 0.f, 0.f};
#pragma unroll
  for (int i = 0; i < 4; i++)
#pragma unroll
    for (int j = 0; j < 4; j++) acc[i][j] = zero;

  for (int k0 = 0; k0 < K; k0 += 128) {
    __syncthreads();
#pragma unroll
    for (int c = 0; c < 4; c++) {
      int kk = k0 + c * 32;
      GL16(pa0 + kk, &la[c][(w * 32) * 32]);
      GL16(pa1 + kk, &la[c][(w * 32 + 16) * 32]);
      GL16(pb0 + kk, &lb[c][(w * 32) * 32]);
      GL16(pb1 + kk, &lb[c][(w * 32 + 16) * 32]);
    }
    __syncthreads();
#pragma unroll
    for (int c = 0; c < 4; c++) {
      short8 af[4], bf[4];
#pragma unroll
      for (int i = 0; i < 4; i++)
        af[i] = *(const short8*)&la[c][(wm * 64 + i * 16 + m) * 32 + g * 8];
#pragma unroll
      for (int j = 0; j < 4; j++)
        bf[j] = *(const short8*)&lb[c][(wn * 64 + j * 16 + m) * 32 + g * 8];
#pragma unroll
      for (int i = 0; i < 4; i++)
#pragma unroll
        for (int j = 0; j < 4; j++)
          acc[i][j] = __builtin_amdgcn_mfma_f32_16x16x32_bf16(af[i], bf[j], acc[i][j], 0, 0, 0);
    }
  }

#pragma unroll
  for (int i = 0; i < 4; i++) {
#pragma unroll
    for (int j = 0; j < 4; j++) {
      int row_l = m0 + wm * 64 + i * 16 + g * 4;
      int col = n0 + wn * 64 + j * 16 + m;
#pragma unroll
      for (int r = 0; r < 4; r++) {
        int row = row_l + r;
        float v = acc[i][j][r];
        if (mode == 0) {
          v += bias[col];
          ((u16*)out)[(size_t)row * N + col] = f2bf(v);
        } else {
          v += bias[row];
          size_t addr = ((size_t)(col >> 12) * M + row) * HW + (col & (HW - 1));
          if (mode == 1) ((u16*)out)[addr] = f2bf(v);
          else           ((float*)out)[addr] = v;
        }
      }
    }
  }
}

// ---------------------------------------------------------------------------
// ppass: P = exp2(Q K^T) materialized bf16 + exact row-sum reciprocals.
// (unchanged from R18 - T14 async-stage split, 32 q-rows/block, XCD swizzle)
// ---------------------------------------------------------------------------
__global__ __launch_bounds__(512) void ppass(
    const u16* __restrict__ qkT, u16* __restrict__ P,
    float* __restrict__ li, int b0) {
  __shared__ u16 kl[256 * 64];
  __shared__ float red[4][32];
  int tid = threadIdx.x;
  int w = tid >> 6, lane = tid & 63, m = lane & 15, g = lane >> 4;
  int total = gridDim.x;
  int hw = blockIdx.x;
  int wk = (hw & 7) * (total >> 3) + (hw >> 3);
  int bb = wk >> 7, b = b0 + bb;
  int q0 = (wk & 127) << 5;
  int qg = w & 1, jh = w >> 1;
  size_t qrow = (size_t)b * HW + q0;

  short8 aq[2];
#pragma unroll
  for (int ks = 0; ks < 2; ks++)
    aq[ks] = *(const short8*)(qkT + (qrow + qg * 16 + m) * 128 + ks * 32 + g * 8);

  float lr[4] = {0.f, 0.f, 0.f, 0.f};
  u16* Pb = P + ((size_t)bb * HW + q0) * HW;
  const u16* kb = qkT + (size_t)b * HW * 128 + 64;
  f32x4 zero = {0.f, 0.f, 0.f, 0.f};

  int prow = tid >> 3, pseg = tid & 7;             // this thread's panel slot
  const u16* psrc = kb + (size_t)prow * 128 + pseg * 8;
  int pdst = prow * 64 + ((pseg ^ (prow & 7)) * 8);

  // prefetch panel 0 into registers
  short8 pf[4];
#pragma unroll
  for (int it = 0; it < 4; it++)
    pf[it] = *(const short8*)(psrc + (size_t)(it * 64) * 128);

  for (int jp = 0; jp < 16; jp++) {
    int j0 = jp * 256;
    __syncthreads();                 // previous compute done reading kl
#pragma unroll
    for (int it = 0; it < 4; it++)
      *(short8*)&kl[pdst + it * 64 * 64] = pf[it];
    if (jp < 15) {                   // issue next panel's loads (hide L2 lat)
#pragma unroll
      for (int it = 0; it < 4; it++)
        pf[it] = *(const short8*)(psrc + (size_t)(j0 + 256 + it * 64) * 128);
    }
    __syncthreads();                 // kl ready
#pragma unroll
    for (int jt = 0; jt < 4; jt++) {
      int jr = jh * 64 + jt * 16;
      int krow = jr + m;
      f32x4 s = zero;
#pragma unroll
      for (int ks = 0; ks < 2; ks++) {
        short8 bk = *(const short8*)&kl[krow * 64 + (((ks * 4 + g) ^ (krow & 7)) * 8)];
        s = __builtin_amdgcn_mfma_f32_16x16x32_bf16(aq[ks], bk, s, 0, 0, 0);
      }
      int j = j0 + jr + m;
#pragma unroll
      for (int r = 0; r < 4; r++) {
        float p = exp2f(s[r]);
        lr[r] += p;
        Pb[(size_t)(qg * 16 + g * 4 + r) * HW + j] = f2bf(p);
      }
    }
  }
#pragma unroll
  for (int r = 0; r < 4; r++) {
#pragma unroll
    for (int off = 1; off < 16; off <<= 1)
      lr[r] += __shfl_xor(lr[r], off);
  }
  __syncthreads();
  if (m == 0) {
#pragma unroll
    for (int r = 0; r < 4; r++) red[jh][qg * 16 + g * 4 + r] = lr[r];
  }
  __syncthreads();
  if (tid < 32)
    li[qrow + tid] = 1.0f / (red[0][tid] + red[1][tid] + red[2][tid] + red[3][tid]);
}

// ---------------------------------------------------------------------------
// gemm_pv: uT = gamma * (P * V^T) .* li + xbT.
// (unchanged - proven R15..R18: 128x128 tile, K-unroll-4, XCD swizzle)
// ---------------------------------------------------------------------------
__global__ __launch_bounds__(256) void gemm_pv(
    const u16* __restrict__ P, const u16* __restrict__ V,
    const float* __restrict__ li, const u16* __restrict__ xbT,
    const float* __restrict__ gamma, u16* __restrict__ uT, int b0) {
  __shared__ u16 la[4][128 * 32];
  __shared__ u16 lb[4][128 * 32];
  int tid = threadIdx.x;
  int w = tid >> 6, lane = tid & 63, m = lane & 15, g = lane >> 4;
  int wm = w >> 1, wn = w & 1;
  int total = gridDim.x * gridDim.y * gridDim.z;
  int lid = blockIdx.x + (blockIdx.y << 2) + (blockIdx.z << 7);
  int wk = (lid & 7) * (total >> 3) + (lid >> 3);
  int chan = (wk & 3) << 7;          // channel quarter: 0,128,256,384
  int q0 = ((wk >> 2) & 31) << 7;    // q-tile of 128
  int bb = wk >> 7, b = b0 + bb;
  int sr = lane >> 2, sc = (lane & 3) * 8;

  const u16* pa0 = P + ((size_t)bb * HW + q0 + w * 32 + sr) * HW + sc;
  const u16* pa1 = pa0 + (size_t)16 * HW;
  const u16* pb0 = V + ((size_t)b * CIN + chan + w * 32 + sr) * HW + sc;
  const u16* pb1 = pb0 + (size_t)16 * HW;

  f32x4 acc[4][4];
  f32x4 zero = {0.f, 0.f, 0.f, 0.f};
#pragma unroll
  for (int i = 0; i < 4; i++)
#pragma unroll
    for (int j = 0; j < 4; j++) acc[i][j] = zero;

  for (int k0 = 0; k0 < HW; k0 += 128) {
    __syncthreads();
#pragma unroll
    for (int c = 0; c < 4; c++) {
      int kk = k0 + c * 32;
      GL16(pa0 + kk, &la[c][(w * 32) * 32]);
      GL16(pa1 + kk, &la[c][(w * 32 + 16) * 32]);
      GL16(pb0 + kk, &lb[c][(w * 32) * 32]);
      GL16(pb1 + kk, &lb[c][(w * 32 + 16) * 32]);
    }
    __syncthreads();
#pragma unroll
    for (int c = 0; c < 4; c++) {
      short8 af[4], bf[4];
#pragma unroll
      for (int i = 0; i < 4; i++)
        af[i] = *(const short8*)&la[c][(wm * 64 + i * 16 + m) * 32 + g * 8];
#pragma unroll
      for (int j = 0; j < 4; j++)
        bf[j] = *(const short8*)&lb[c][(wn * 64 + j * 16 + m) * 32 + g * 8];
#pragma unroll
      for (int i = 0; i < 4; i++)
#pragma unroll
        for (int j = 0; j < 4; j++)
          acc[i][j] = __builtin_amdgcn_mfma_f32_16x16x32_bf16(af[i], bf[j], acc[i][j], 0, 0, 0);
    }
  }

  float gm = gamma[0];
#pragma unroll
  for (int i = 0; i < 4; i++) {
#pragma unroll
    for (int j = 0; j < 4; j++) {
#pragma unroll
      for (int r = 0; r < 4; r++) {
        int q = q0 + wm * 64 + i * 16 + g * 4 + r;
        int c = chan + wn * 64 + j * 16 + m;
        size_t row = (size_t)b * HW + q;
        float o = acc[i][j][r] * li[row];
        float xv = bf2f(xbT[row * CIN + c]);
        uT[row * CIN + c] = f2bf(gm * o + xv);
      }
    }
  }
}

// ---------------------------------------------------------------------------
extern "C" void kernel_launch(void* const* d_in, const int* in_sizes, int n_in,
                              void* d_out, int out_size, void* d_ws, size_t ws_size,
                              hipStream_t stream) {
  const float* x     = (const float*)d_in[0];
  const float* Wq    = (const float*)d_in[1];
  const float* bq    = (const float*)d_in[2];
  const float* Wk    = (const float*)d_in[3];
  const float* bk    = (const float*)d_in[4];
  const float* Wv    = (const float*)d_in[5];
  const float* bv    = (const float*)d_in[6];
  const float* gamma = (const float*)d_in[7];
  const float* Wd    = (const float*)d_in[8];
  const float* bd    = (const float*)d_in[9];

  char* ws = (char*)d_ws;
  size_t off = 0;
  auto alloc = [&](size_t bytes) {
    void* p = ws + off;
    off += (bytes + 255) & ~(size_t)255;
    return p;
  };
  u16*   xbT = (u16*)alloc((size_t)16384 * 512 * 2);
  u16*   qkT = (u16*)alloc((size_t)16384 * 128 * 2);
  u16*   vb  = (u16*)alloc((size_t)16384 * 512 * 2);
  u16*   uT  = (u16*)alloc((size_t)16384 * 512 * 2);
  u16*   wqk = (u16*)alloc((size_t)65536 * 2);
  u16*   wvb = (u16*)alloc((size_t)262144 * 2);
  u16*   wdb = (u16*)alloc((size_t)262144 * 2);
  float* bqk = (float*)alloc(128 * 4);
  float* li  = (float*)alloc((size_t)16384 * 4);
  size_t PB = (size_t)HW * HW * 2;
  int nb = 0;
  if      (off + 4 * PB <= ws_size) nb = 4;
  else if (off + 2 * PB <= ws_size) nb = 2;
  else if (off + 1 * PB <= ws_size) nb = 1;
  if (nb == 0) return;  // workspace too small -> poison stays -> loud failure
  u16* Pbuf = (u16*)alloc(nb * PB);

  cast_xT<<<dim3(64, 8, 4), 256, 0, stream>>>(x, xbT);
  cast_w<<<1024, 256, 0, stream>>>(Wq, Wk, Wv, Wd, bq, bk, wqk, wvb, wdb, bqk);
  // qkT (16384,128) = xbT * wqk^T  (dedicated small-N kernel, 256 blocks)
  qk_gemm<<<256, 256, 0, stream>>>(xbT, wqk, bqk, qkT);
  // v (B,512,HW) = Wv * x
  gemm_bf16<<<dim3(128, 4), 256, 0, stream>>>(wvb, xbT, bv, vb, 512, 16384, 512, 1);
  // attention: P materialize + PV GEMM (staged by batch groups of nb)
  for (int b0 = 0; b0 < 4; b0 += nb) {
    ppass<<<dim3(nb * 128), 512, 0, stream>>>(qkT, Pbuf, li, b0);
    gemm_pv<<<dim3(4, 32, nb), 256, 0, stream>>>(Pbuf, vb, li, xbT, gamma, uT, b0);
  }
  // pam_out (B,512,HW) fp32 = Wd * u
  gemm_bf16<<<dim3(128, 4), 256, 0, stream>>>(wdb, uT, bd, d_out, 512, 16384, 512, 2);
}